// Round 1
// baseline (908.758 us; speedup 1.0000x reference)
//
#include <hip/hip_runtime.h>

typedef __bf16 bf16x8 __attribute__((ext_vector_type(8)));
typedef float f32x4 __attribute__((ext_vector_type(4)));

__device__ __forceinline__ unsigned short f2bf(float f) {
    union { float f; unsigned int u; } x; x.f = f;
    unsigned int r = x.u + 0x7FFFu + ((x.u >> 16) & 1u);
    return (unsigned short)(r >> 16);
}
__device__ __forceinline__ float bf2f(unsigned short v) {
    union { unsigned int u; float f; } x; x.u = ((unsigned int)v) << 16; return x.f;
}
__device__ __forceinline__ float bf2f_lo(unsigned int w) {
    union { unsigned int u; float f; } x; x.u = w << 16; return x.f;
}
__device__ __forceinline__ float bf2f_hi(unsigned int w) {
    union { unsigned int u; float f; } x; x.u = w & 0xffff0000u; return x.f;
}
__device__ __forceinline__ unsigned int cvt_pk_bf16(float lo, float hi) {
    unsigned int r;
    asm("v_cvt_pk_bf16_f32 %0, %1, %2" : "=v"(r) : "v"(lo), "v"(hi));
    return r;
}
// async global->LDS, 16B per lane. LDS dest must be lane-linear (wave base + lane*16).
__device__ __forceinline__ void async16(const void* g, void* l) {
    __builtin_amdgcn_global_load_lds(
        (const __attribute__((address_space(1))) unsigned int*)g,
        (__attribute__((address_space(3))) unsigned int*)l, 16, 0, 0);
}

// ---------------- Kernel 0a: pre-convert Wv1 [512x512] and Wv2 [256x512] to bf16
__global__ __launch_bounds__(256) void k_prep(
    const float* __restrict__ Wv1, const float* __restrict__ Wv2,
    unsigned short* __restrict__ Wv1bf, unsigned short* __restrict__ Wv2bf)
{
    int idx = blockIdx.x * 256 + threadIdx.x;
    if (idx < 262144) {
        Wv1bf[idx] = f2bf(Wv1[idx]);
    } else {
        int j = idx - 262144;           // < 131072
        Wv2bf[j] = f2bf(Wv2[j]);
    }
}

// ---------------- Kernel 0b: pre-convert video [2560*49*512] fp32 -> bf16 (linear layout)
__global__ __launch_bounds__(256) void k_prepv(
    const float* __restrict__ v, unsigned short* __restrict__ vbf)
{
    const size_t stride = (size_t)gridDim.x * 256;
    for (size_t c = (size_t)blockIdx.x * 256 + threadIdx.x; c < 8028160u; c += stride) {
        const float* p = v + c * 8;
        float4 a = *(const float4*)p;
        float4 b = *(const float4*)(p + 4);
        uint4 o;
        o.x = cvt_pk_bf16(a.x, a.y); o.y = cvt_pk_bf16(a.z, a.w);
        o.z = cvt_pk_bf16(b.x, b.y); o.w = cvt_pk_bf16(b.z, b.w);
        *(uint4*)(vbf + c * 8) = o;
    }
}

// ---------------- Kernel 1: aq1 = relu(af@Wa1^T+ba1), aq2 = relu(af@Wa2^T+ba2)
__global__ __launch_bounds__(256) void k_audio(
    const float* __restrict__ audio,
    const float* __restrict__ Wa1, const float* __restrict__ ba1,
    const float* __restrict__ Wa2, const float* __restrict__ ba2,
    float* __restrict__ aq1, float* __restrict__ aq2)
{
    __shared__ float afs[4][128];
    const int btBase = blockIdx.x * 4;
    const int tid = threadIdx.x;
    for (int i = tid; i < 512; i += 256) {
        int g = i >> 7, k = i & 127;
        int bt = btBase + g;
        int b = bt / 10, t = bt - b * 10;
        afs[g][k] = audio[(t * 256 + b) * 128 + k];
    }
    __syncthreads();
    const int c = tid;  // 0..255
    float a1a[4] = {0.f,0.f,0.f,0.f}, a1b[4] = {0.f,0.f,0.f,0.f}, a2[4] = {0.f,0.f,0.f,0.f};
    const float* w1a = Wa1 + c * 128;
    const float* w1b = Wa1 + (c + 256) * 128;
    const float* w2p = Wa2 + c * 128;
    for (int kk = 0; kk < 32; ++kk) {
        float4 va = *(const float4*)(w1a + kk * 4);
        float4 vb = *(const float4*)(w1b + kk * 4);
        float4 vc = *(const float4*)(w2p + kk * 4);
        float fa[4] = {va.x, va.y, va.z, va.w};
        float fb[4] = {vb.x, vb.y, vb.z, vb.w};
        float fc[4] = {vc.x, vc.y, vc.z, vc.w};
#pragma unroll
        for (int j = 0; j < 4; ++j) {
            int k = kk * 4 + j;
#pragma unroll
            for (int g = 0; g < 4; ++g) {
                float a = afs[g][k];
                a1a[g] += a * fa[j];
                a1b[g] += a * fb[j];
                a2[g]  += a * fc[j];
            }
        }
    }
    float b1a = ba1[c], b1b = ba1[c + 256], b2 = ba2[c];
#pragma unroll
    for (int g = 0; g < 4; ++g) {
        int bt = btBase + g;
        aq1[bt * 512 + c]       = fmaxf(a1a[g] + b1a, 0.f);
        aq1[bt * 512 + c + 256] = fmaxf(a1b[g] + b1b, 0.f);
        aq2[bt * 256 + c]       = fmaxf(a2[g] + b2, 0.f);
    }
}

// ---------------- Kernel 2: avq[bt,n] = aq1[bt,n] * mean_hw relu(vf@Wv1^T + bv1)
// bf16 video staged via async global_load_lds with pre-swizzled source addresses.
// N split into 2 passes (acc[4][4]) to cut register pressure -> 3 blocks/CU.
__global__ __launch_bounds__(256) void k_chanatt(
    const unsigned short* __restrict__ videobf,
    const unsigned short* __restrict__ Wv1bf, const float* __restrict__ bv1,
    const float* __restrict__ aq1, float* __restrict__ avq)
{
    __shared__ unsigned short At[49 * 512];  // bf16, XOR chunk-swizzled
    const int bt = blockIdx.x;
    const int tid = threadIdx.x;
    const int wave = tid >> 6, lane = tid & 63, quad = lane >> 4, l16 = lane & 15;
    const unsigned short* vsrc = videobf + (size_t)bt * 25088;

    // 3136 chunks of 16B. LDS linear; global source pre-swizzled: chunk p holds ch = (p&63)^(row&7).
#pragma unroll
    for (int i = 0; i < 13; ++i) {
        int p = i * 256 + tid;
        if (p < 3136) {
            int row = p >> 6;
            int ch = (p & 63) ^ (row & 7);
            async16(vsrc + row * 512 + ch * 8, &At[p * 8]);
        }
    }
    __syncthreads();   // drains vmcnt -> tile ready

#pragma unroll 1
    for (int npass = 0; npass < 2; ++npass) {
        f32x4 acc[4][4];
#pragma unroll
        for (int mt = 0; mt < 4; ++mt)
#pragma unroll
            for (int nt = 0; nt < 4; ++nt)
                acc[mt][nt] = (f32x4){0.f, 0.f, 0.f, 0.f};

        for (int kk = 0; kk < 16; ++kk) {
            int chunk = kk * 4 + quad;   // k-group of 8; koff = chunk*8
            bf16x8 afrag[4];
#pragma unroll
            for (int mt = 0; mt < 4; ++mt) {
                int m = ((mt == 3) ? 33 : mt * 16) + l16;
                int chs = chunk ^ (m & 7);
                afrag[mt] = *(const bf16x8*)(&At[m * 512 + chs * 8]);
            }
            int koff = chunk * 8;
#pragma unroll
            for (int nt = 0; nt < 4; ++nt) {
                int n = (wave * 8 + npass * 4 + nt) * 16 + l16;
                bf16x8 bfrag = *(const bf16x8*)(Wv1bf + n * 512 + koff);
#pragma unroll
                for (int mt = 0; mt < 4; ++mt)
                    acc[mt][nt] = __builtin_amdgcn_mfma_f32_16x16x32_bf16(
                        afrag[mt], bfrag, acc[mt][nt], 0, 0, 0);
            }
        }

#pragma unroll
        for (int nt = 0; nt < 4; ++nt) {
            int n = (wave * 8 + npass * 4 + nt) * 16 + l16;
            float bias = bv1[n];
            float s = 0.f;
#pragma unroll
            for (int mt = 0; mt < 4; ++mt)
#pragma unroll
                for (int r = 0; r < 4; ++r)
                    if (mt < 3 || (quad == 3 && r == 3))
                        s += fmaxf(acc[mt][nt][r] + bias, 0.f);
            s += __shfl_xor(s, 16, 64);
            s += __shfl_xor(s, 32, 64);
            if (quad == 0) {
                float vm = s * (1.f / 49.f);
                avq[bt * 512 + n] = aq1[bt * 512 + n] * vm;
            }
        }
    }
}

// ---------------- Kernel 3: cmul = 1 + sigmoid( relu(avq@Wb^T+bb) @ Wc^T + bc )
__global__ __launch_bounds__(256) void k_mlp(
    const float* __restrict__ avq,
    const float* __restrict__ Wb, const float* __restrict__ bb,
    const float* __restrict__ Wc, const float* __restrict__ bc,
    float* __restrict__ cmul)
{
    __shared__ float av[4][512];
    __shared__ float hid[4][256];
    const int btBase = blockIdx.x * 4;
    const int tid = threadIdx.x;
    for (int i = tid; i < 2048; i += 256) {
        int g = i >> 9, c = i & 511;
        av[g][c] = avq[(btBase + g) * 512 + c];
    }
    __syncthreads();
    {
        float a[4] = {0.f,0.f,0.f,0.f};
        const float* wrow = Wb + tid * 512;
        for (int kk = 0; kk < 128; ++kk) {
            float4 v = *(const float4*)(wrow + kk * 4);
            float w[4] = {v.x, v.y, v.z, v.w};
#pragma unroll
            for (int j = 0; j < 4; ++j)
#pragma unroll
                for (int g = 0; g < 4; ++g)
                    a[g] += av[g][kk * 4 + j] * w[j];
        }
        float bias = bb[tid];
#pragma unroll
        for (int g = 0; g < 4; ++g) hid[g][tid] = fmaxf(a[g] + bias, 0.f);
    }
    __syncthreads();
#pragma unroll
    for (int rep = 0; rep < 2; ++rep) {
        int c = tid + rep * 256;
        float a[4] = {0.f,0.f,0.f,0.f};
        const float* wrow = Wc + c * 256;
        for (int kk = 0; kk < 64; ++kk) {
            float4 v = *(const float4*)(wrow + kk * 4);
            float w[4] = {v.x, v.y, v.z, v.w};
#pragma unroll
            for (int j = 0; j < 4; ++j)
#pragma unroll
                for (int g = 0; g < 4; ++g)
                    a[g] += hid[g][kk * 4 + j] * w[j];
        }
        float bias = bc[c];
#pragma unroll
        for (int g = 0; g < 4; ++g) {
            float s = 1.f / (1.f + __expf(-(a[g] + bias)));
            cmul[(btBase + g) * 512 + c] = 1.f + s;
        }
    }
}

// ---------------- Kernel 4: spatial attention + output, per bt
// bf16 video staged async; tile scaled by cmul in-LDS (one thread owns one channel-group).
__global__ __launch_bounds__(256) void k_spatial(
    const unsigned short* __restrict__ videobf,
    const float* __restrict__ cmul, const float* __restrict__ aq2,
    const unsigned short* __restrict__ Wv2bf, const float* __restrict__ bv2,
    const float* __restrict__ Wsp, const float* __restrict__ bsp,
    float* __restrict__ out)
{
    __shared__ unsigned short Ct[49 * 512];  // c_att bf16, XOR chunk-swizzled
    __shared__ float w2[256];
    __shared__ float zbuf[4][64];
    __shared__ float smw[64];
    const int bt = blockIdx.x;
    const int tid = threadIdx.x;
    const int wave = tid >> 6, lane = tid & 63, quad = lane >> 4, l16 = lane & 15;
    const unsigned short* vsrc = videobf + (size_t)bt * 25088;

#pragma unroll
    for (int i = 0; i < 13; ++i) {
        int p = i * 256 + tid;
        if (p < 3136) {
            int row = p >> 6;
            int ch = (p & 63) ^ (row & 7);
            async16(vsrc + row * 512 + ch * 8, &Ct[p * 8]);
        }
    }
    // non-LDS-tile work overlaps with the async loads
    w2[tid] = aq2[bt * 256 + tid] * Wsp[tid];
    if (lane >= 49) zbuf[wave][lane] = 0.f;   // rows 49..63 never written below
    const int ch0 = tid & 63, rg = tid >> 6;
    float cmv[8];
    {
        const float* cmp = cmul + bt * 512 + ch0 * 8;
        float4 c0 = *(const float4*)cmp;
        float4 c1 = *(const float4*)(cmp + 4);
        cmv[0]=c0.x; cmv[1]=c0.y; cmv[2]=c0.z; cmv[3]=c0.w;
        cmv[4]=c1.x; cmv[5]=c1.y; cmv[6]=c1.z; cmv[7]=c1.w;
    }
    __syncthreads();   // video tile resident

    // scale pass: thread owns physical channel-group ch0, rows rg, rg+4, ... (race-free RMW)
#pragma unroll
    for (int row = rg; row < 49; row += 4) {
        int chs = ch0 ^ (row & 7);
        uint4* p = (uint4*)(&Ct[row * 512 + chs * 8]);
        uint4 v = *p;
        unsigned int w[4] = {v.x, v.y, v.z, v.w};
        uint4 o;
        o.x = cvt_pk_bf16(bf2f_lo(w[0]) * cmv[0], bf2f_hi(w[0]) * cmv[1]);
        o.y = cvt_pk_bf16(bf2f_lo(w[1]) * cmv[2], bf2f_hi(w[1]) * cmv[3]);
        o.z = cvt_pk_bf16(bf2f_lo(w[2]) * cmv[4], bf2f_hi(w[2]) * cmv[5]);
        o.w = cvt_pk_bf16(bf2f_lo(w[3]) * cmv[6], bf2f_hi(w[3]) * cmv[7]);
        *p = o;
    }
    __syncthreads();

    f32x4 acc[4][4];
#pragma unroll
    for (int mt = 0; mt < 4; ++mt)
#pragma unroll
        for (int nt = 0; nt < 4; ++nt)
            acc[mt][nt] = (f32x4){0.f, 0.f, 0.f, 0.f};

    for (int kk = 0; kk < 16; ++kk) {
        int chunk = kk * 4 + quad;
        bf16x8 afrag[4];
#pragma unroll
        for (int mt = 0; mt < 4; ++mt) {
            int m = ((mt == 3) ? 33 : mt * 16) + l16;
            int chs = chunk ^ (m & 7);
            afrag[mt] = *(const bf16x8*)(&Ct[m * 512 + chs * 8]);
        }
        int koff = chunk * 8;
#pragma unroll
        for (int nt = 0; nt < 4; ++nt) {
            int n = (wave * 4 + nt) * 16 + l16;
            bf16x8 bfrag = *(const bf16x8*)(Wv2bf + n * 512 + koff);
#pragma unroll
            for (int mt = 0; mt < 4; ++mt)
                acc[mt][nt] = __builtin_amdgcn_mfma_f32_16x16x32_bf16(
                    afrag[mt], bfrag, acc[mt][nt], 0, 0, 0);
        }
    }

    // zp[mt*4+r] = sum over this wave's 64 cols of relu(cq + bias) * aq2 * Ws
    float zp[16];
#pragma unroll
    for (int i = 0; i < 16; ++i) zp[i] = 0.f;
#pragma unroll
    for (int nt = 0; nt < 4; ++nt) {
        int n = (wave * 4 + nt) * 16 + l16;
        float bias = bv2[n];
        float wn = w2[n];
#pragma unroll
        for (int mt = 0; mt < 4; ++mt)
#pragma unroll
            for (int r = 0; r < 4; ++r)
                zp[mt * 4 + r] += fmaxf(acc[mt][nt][r] + bias, 0.f) * wn;
    }
#pragma unroll
    for (int i = 0; i < 16; ++i) {
        float v = zp[i];
        v += __shfl_xor(v, 1, 64);
        v += __shfl_xor(v, 2, 64);
        v += __shfl_xor(v, 4, 64);
        v += __shfl_xor(v, 8, 64);
        zp[i] = v;
    }
    if (l16 == 0) {
#pragma unroll
        for (int mt = 0; mt < 4; ++mt)
#pragma unroll
            for (int r = 0; r < 4; ++r)
                if (mt < 3 || (quad == 3 && r == 3)) {
                    int row = ((mt == 3) ? 33 : mt * 16) + quad * 4 + r;
                    zbuf[wave][row] = zp[mt * 4 + r];
                }
    }
    __syncthreads();

    if (wave == 0) {
        int hw = lane;
        float z = zbuf[0][hw] + zbuf[1][hw] + zbuf[2][hw] + zbuf[3][hw] + bsp[0];
        float t = tanhf(z);
        float v = (hw < 49) ? t : -1e30f;
#pragma unroll
        for (int off = 32; off; off >>= 1) v = fmaxf(v, __shfl_xor(v, off, 64));
        float e = (hw < 49) ? __expf(t - v) : 0.f;
        float se = e;
#pragma unroll
        for (int off = 32; off; off >>= 1) se += __shfl_xor(se, off, 64);
        smw[hw] = e / se;
    }
    __syncthreads();

#pragma unroll
    for (int rep = 0; rep < 2; ++rep) {
        int cidx = tid + rep * 256;
        int chb = cidx >> 3, jj = cidx & 7;
        float s = 0.f;
        for (int hw = 0; hw < 49; ++hw) {
            int chs = chb ^ (hw & 7);
            s += smw[hw] * bf2f(Ct[hw * 512 + chs * 8 + jj]);
        }
        out[bt * 512 + cidx] = s;
    }
}

// ================= Fallback kernels (original fp32-video path, used if ws too small) ======
__global__ __launch_bounds__(256) void k_chanatt_fb(
    const float* __restrict__ video,
    const unsigned short* __restrict__ Wv1bf, const float* __restrict__ bv1,
    const float* __restrict__ aq1, float* __restrict__ avq)
{
    __shared__ unsigned short At[49 * 512];
    const int bt = blockIdx.x;
    const int tid = threadIdx.x;
    const int wave = tid >> 6, lane = tid & 63, quad = lane >> 4, l16 = lane & 15;
    const float* vsrc = video + (size_t)bt * 25088;

    for (int c = tid; c < 3136; c += 256) {
        int row = c >> 6, ch = c & 63;
        float4 a = *(const float4*)(vsrc + row * 512 + ch * 8);
        float4 b = *(const float4*)(vsrc + row * 512 + ch * 8 + 4);
        float f[8] = {a.x, a.y, a.z, a.w, b.x, b.y, b.z, b.w};
        unsigned int o[8];
#pragma unroll
        for (int j = 0; j < 8; ++j) o[j] = f2bf(f[j]);
        uint4 pack;
        pack.x = o[0] | (o[1] << 16); pack.y = o[2] | (o[3] << 16);
        pack.z = o[4] | (o[5] << 16); pack.w = o[6] | (o[7] << 16);
        int chs = ch ^ (row & 7);
        *(uint4*)(&At[row * 512 + chs * 8]) = pack;
    }
    __syncthreads();

    f32x4 acc[4][8];
#pragma unroll
    for (int mt = 0; mt < 4; ++mt)
#pragma unroll
        for (int nt = 0; nt < 8; ++nt)
            acc[mt][nt] = (f32x4){0.f, 0.f, 0.f, 0.f};

    for (int kk = 0; kk < 16; ++kk) {
        int chunk = kk * 4 + quad;
        bf16x8 afrag[4];
#pragma unroll
        for (int mt = 0; mt < 4; ++mt) {
            int m = ((mt == 3) ? 33 : mt * 16) + l16;
            int chs = chunk ^ (m & 7);
            afrag[mt] = *(const bf16x8*)(&At[m * 512 + chs * 8]);
        }
        int koff = chunk * 8;
#pragma unroll
        for (int nt = 0; nt < 8; ++nt) {
            int n = (wave * 8 + nt) * 16 + l16;
            bf16x8 bfrag = *(const bf16x8*)(Wv1bf + n * 512 + koff);
#pragma unroll
            for (int mt = 0; mt < 4; ++mt)
                acc[mt][nt] = __builtin_amdgcn_mfma_f32_16x16x32_bf16(
                    afrag[mt], bfrag, acc[mt][nt], 0, 0, 0);
        }
    }

#pragma unroll
    for (int nt = 0; nt < 8; ++nt) {
        int n = (wave * 8 + nt) * 16 + l16;
        float bias = bv1[n];
        float s = 0.f;
#pragma unroll
        for (int mt = 0; mt < 4; ++mt)
#pragma unroll
            for (int r = 0; r < 4; ++r)
                if (mt < 3 || (quad == 3 && r == 3))
                    s += fmaxf(acc[mt][nt][r] + bias, 0.f);
        s += __shfl_xor(s, 16, 64);
        s += __shfl_xor(s, 32, 64);
        if (quad == 0) {
            float vm = s * (1.f / 49.f);
            avq[bt * 512 + n] = aq1[bt * 512 + n] * vm;
        }
    }
}

__global__ __launch_bounds__(256) void k_spatial_fb(
    const float* __restrict__ video,
    const float* __restrict__ cmul, const float* __restrict__ aq2,
    const unsigned short* __restrict__ Wv2bf, const float* __restrict__ bv2,
    const float* __restrict__ Wsp, const float* __restrict__ bsp,
    float* __restrict__ out)
{
    __shared__ unsigned short Ct[49 * 512];
    __shared__ float w2[256];
    __shared__ float zbuf[4][64];
    __shared__ float smw[64];
    const int bt = blockIdx.x;
    const int tid = threadIdx.x;
    const int wave = tid >> 6, lane = tid & 63, quad = lane >> 4, l16 = lane & 15;
    const float* vsrc = video + (size_t)bt * 25088;
    const float* cm = cmul + bt * 512;

    for (int c = tid; c < 3136; c += 256) {
        int row = c >> 6, ch = c & 63;
        float4 a = *(const float4*)(vsrc + row * 512 + ch * 8);
        float4 b = *(const float4*)(vsrc + row * 512 + ch * 8 + 4);
        float f[8] = {a.x, a.y, a.z, a.w, b.x, b.y, b.z, b.w};
        float4 m0 = *(const float4*)(cm + ch * 8);
        float4 m1 = *(const float4*)(cm + ch * 8 + 4);
        float mm[8] = {m0.x, m0.y, m0.z, m0.w, m1.x, m1.y, m1.z, m1.w};
        unsigned int o[8];
#pragma unroll
        for (int j = 0; j < 8; ++j) o[j] = f2bf(f[j] * mm[j]);
        uint4 pack;
        pack.x = o[0] | (o[1] << 16); pack.y = o[2] | (o[3] << 16);
        pack.z = o[4] | (o[5] << 16); pack.w = o[6] | (o[7] << 16);
        int chs = ch ^ (row & 7);
        *(uint4*)(&Ct[row * 512 + chs * 8]) = pack;
    }
    w2[tid] = aq2[bt * 256 + tid] * Wsp[tid];
    if (lane >= 49) zbuf[wave][lane] = 0.f;
    __syncthreads();

    f32x4 acc[4][4];
#pragma unroll
    for (int mt = 0; mt < 4; ++mt)
#pragma unroll
        for (int nt = 0; nt < 4; ++nt)
            acc[mt][nt] = (f32x4){0.f, 0.f, 0.f, 0.f};

    for (int kk = 0; kk < 16; ++kk) {
        int chunk = kk * 4 + quad;
        bf16x8 afrag[4];
#pragma unroll
        for (int mt = 0; mt < 4; ++mt) {
            int m = ((mt == 3) ? 33 : mt * 16) + l16;
            int chs = chunk ^ (m & 7);
            afrag[mt] = *(const bf16x8*)(&Ct[m * 512 + chs * 8]);
        }
        int koff = chunk * 8;
#pragma unroll
        for (int nt = 0; nt < 4; ++nt) {
            int n = (wave * 4 + nt) * 16 + l16;
            bf16x8 bfrag = *(const bf16x8*)(Wv2bf + n * 512 + koff);
#pragma unroll
            for (int mt = 0; mt < 4; ++mt)
                acc[mt][nt] = __builtin_amdgcn_mfma_f32_16x16x32_bf16(
                    afrag[mt], bfrag, acc[mt][nt], 0, 0, 0);
        }
    }

    float zp[16];
#pragma unroll
    for (int i = 0; i < 16; ++i) zp[i] = 0.f;
#pragma unroll
    for (int nt = 0; nt < 4; ++nt) {
        int n = (wave * 4 + nt) * 16 + l16;
        float bias = bv2[n];
        float wn = w2[n];
#pragma unroll
        for (int mt = 0; mt < 4; ++mt)
#pragma unroll
            for (int r = 0; r < 4; ++r)
                zp[mt * 4 + r] += fmaxf(acc[mt][nt][r] + bias, 0.f) * wn;
    }
#pragma unroll
    for (int i = 0; i < 16; ++i) {
        float v = zp[i];
        v += __shfl_xor(v, 1, 64);
        v += __shfl_xor(v, 2, 64);
        v += __shfl_xor(v, 4, 64);
        v += __shfl_xor(v, 8, 64);
        zp[i] = v;
    }
    if (l16 == 0) {
#pragma unroll
        for (int mt = 0; mt < 4; ++mt)
#pragma unroll
            for (int r = 0; r < 4; ++r)
                if (mt < 3 || (quad == 3 && r == 3)) {
                    int row = ((mt == 3) ? 33 : mt * 16) + quad * 4 + r;
                    zbuf[wave][row] = zp[mt * 4 + r];
                }
    }
    __syncthreads();

    if (wave == 0) {
        int hw = lane;
        float z = zbuf[0][hw] + zbuf[1][hw] + zbuf[2][hw] + zbuf[3][hw] + bsp[0];
        float t = tanhf(z);
        float v = (hw < 49) ? t : -1e30f;
#pragma unroll
        for (int off = 32; off; off >>= 1) v = fmaxf(v, __shfl_xor(v, off, 64));
        float e = (hw < 49) ? __expf(t - v) : 0.f;
        float se = e;
#pragma unroll
        for (int off = 32; off; off >>= 1) se += __shfl_xor(se, off, 64);
        smw[hw] = e / se;
    }
    __syncthreads();

#pragma unroll
    for (int rep = 0; rep < 2; ++rep) {
        int cidx = tid + rep * 256;
        int chb = cidx >> 3, jj = cidx & 7;
        float s = 0.f;
        for (int hw = 0; hw < 49; ++hw) {
            int chs = chb ^ (hw & 7);
            s += smw[hw] * bf2f(Ct[hw * 512 + chs * 8 + jj]);
        }
        out[bt * 512 + cidx] = s;
    }
}

extern "C" void kernel_launch(void* const* d_in, const int* in_sizes, int n_in,
                              void* d_out, int out_size, void* d_ws, size_t ws_size,
                              hipStream_t stream) {
    const float* video = (const float*)d_in[0];
    const float* audio = (const float*)d_in[1];
    const float* Wv1 = (const float*)d_in[2];
    const float* bv1 = (const float*)d_in[3];
    const float* Wa1 = (const float*)d_in[4];
    const float* ba1 = (const float*)d_in[5];
    const float* Wb  = (const float*)d_in[6];
    const float* bb  = (const float*)d_in[7];
    const float* Wc  = (const float*)d_in[8];
    const float* bc  = (const float*)d_in[9];
    const float* Wv2 = (const float*)d_in[10];
    const float* bv2 = (const float*)d_in[11];
    const float* Wa2 = (const float*)d_in[12];
    const float* ba2 = (const float*)d_in[13];
    const float* Wsp = (const float*)d_in[14];
    const float* bsp = (const float*)d_in[15];
    float* out = (float*)d_out;

    // new path needs: videobf 128,450,560 + Wv1bf 524,288 + Wv2bf 262,144
    //                + 4 f32 arrays 18,350,080 = 147,587,072 bytes
    const size_t NEED = 147587072u;
    if (ws_size >= NEED) {
        unsigned short* videobf = (unsigned short*)d_ws;        // 64,225,280 shorts
        unsigned short* Wv1bf = videobf + 64225280;             // 262,144
        unsigned short* Wv2bf = Wv1bf + 262144;                 // 131,072
        float* fbase = (float*)(Wv2bf + 131072);
        float* aq1  = fbase;                    // [2560,512]
        float* aq2  = aq1 + 1310720;            // [2560,256]
        float* avq  = aq2 + 655360;             // [2560,512]
        float* cmul = avq + 1310720;            // [2560,512]

        k_prep<<<1536, 256, 0, stream>>>(Wv1, Wv2, Wv1bf, Wv2bf);
        k_audio<<<640, 256, 0, stream>>>(audio, Wa1, ba1, Wa2, ba2, aq1, aq2);
        k_prepv<<<4096, 256, 0, stream>>>(video, videobf);
        k_chanatt<<<2560, 256, 0, stream>>>(videobf, Wv1bf, bv1, aq1, avq);
        k_mlp<<<640, 256, 0, stream>>>(avq, Wb, bb, Wc, bc, cmul);
        k_spatial<<<2560, 256, 0, stream>>>(videobf, cmul, aq2, Wv2bf, bv2, Wsp, bsp, out);
    } else {
        float* ws = (float*)d_ws;
        float* aq1  = ws;                       // [2560,512]
        float* aq2  = aq1 + 1310720;            // [2560,256]
        float* avq  = aq2 + 655360;             // [2560,512]
        float* cmul = avq + 1310720;            // [2560,512]
        unsigned short* Wv1bf = (unsigned short*)(cmul + 1310720);  // 512x512
        unsigned short* Wv2bf = Wv1bf + 262144;                     // 256x512

        k_prep<<<1536, 256, 0, stream>>>(Wv1, Wv2, Wv1bf, Wv2bf);
        k_audio<<<640, 256, 0, stream>>>(audio, Wa1, ba1, Wa2, ba2, aq1, aq2);
        k_chanatt_fb<<<2560, 256, 0, stream>>>(video, Wv1bf, bv1, aq1, avq);
        k_mlp<<<640, 256, 0, stream>>>(avq, Wb, bb, Wc, bc, cmul);
        k_spatial_fb<<<2560, 256, 0, stream>>>(video, cmul, aq2, Wv2bf, bv2, Wsp, bsp, out);
    }
}

// Round 2
// 756.959 us; speedup vs baseline: 1.2005x; 1.2005x over previous
//
#include <hip/hip_runtime.h>

typedef __bf16 bf16x8 __attribute__((ext_vector_type(8)));
typedef float f32x4 __attribute__((ext_vector_type(4)));

__device__ __forceinline__ unsigned short f2bf(float f) {
    union { float f; unsigned int u; } x; x.f = f;
    unsigned int r = x.u + 0x7FFFu + ((x.u >> 16) & 1u);
    return (unsigned short)(r >> 16);
}
__device__ __forceinline__ float bf2f(unsigned short v) {
    union { unsigned int u; float f; } x; x.u = ((unsigned int)v) << 16; return x.f;
}
__device__ __forceinline__ float bf2f_lo(unsigned int w) {
    union { unsigned int u; float f; } x; x.u = w << 16; return x.f;
}
__device__ __forceinline__ float bf2f_hi(unsigned int w) {
    union { unsigned int u; float f; } x; x.u = w & 0xffff0000u; return x.f;
}
__device__ __forceinline__ unsigned int cvt_pk_bf16(float lo, float hi) {
    unsigned int r;
    asm("v_cvt_pk_bf16_f32 %0, %1, %2" : "=v"(r) : "v"(lo), "v"(hi));
    return r;
}
// async global->LDS, 16B per lane. LDS dest must be lane-linear within a wave.
__device__ __forceinline__ void async16(const void* g, void* l) {
    __builtin_amdgcn_global_load_lds(
        (const __attribute__((address_space(1))) unsigned int*)g,
        (__attribute__((address_space(3))) unsigned int*)l, 16, 0, 0);
}

// ---------------- Kernel 0a: pre-convert Wv1 [512x512] and Wv2 [256x512] to bf16
__global__ __launch_bounds__(256) void k_prep(
    const float* __restrict__ Wv1, const float* __restrict__ Wv2,
    unsigned short* __restrict__ Wv1bf, unsigned short* __restrict__ Wv2bf)
{
    int idx = blockIdx.x * 256 + threadIdx.x;
    if (idx < 262144) {
        Wv1bf[idx] = f2bf(Wv1[idx]);
    } else {
        int j = idx - 262144;           // < 131072
        Wv2bf[j] = f2bf(Wv2[j]);
    }
}

// ---------------- Kernel 0b: pre-convert video [2560*49*512] fp32 -> bf16 (linear)
__global__ __launch_bounds__(256) void k_prepv(
    const float* __restrict__ v, unsigned short* __restrict__ vbf)
{
    const size_t stride = (size_t)gridDim.x * 256;
    for (size_t c = (size_t)blockIdx.x * 256 + threadIdx.x; c < 8028160u; c += stride) {
        const float* p = v + c * 8;
        float4 a = *(const float4*)p;
        float4 b = *(const float4*)(p + 4);
        uint4 o;
        o.x = cvt_pk_bf16(a.x, a.y); o.y = cvt_pk_bf16(a.z, a.w);
        o.z = cvt_pk_bf16(b.x, b.y); o.w = cvt_pk_bf16(b.z, b.w);
        *(uint4*)(vbf + c * 8) = o;
    }
}

// ---------------- Kernel 1: aq1 = relu(af@Wa1^T+ba1), aq2 = relu(af@Wa2^T+ba2)
__global__ __launch_bounds__(256) void k_audio(
    const float* __restrict__ audio,
    const float* __restrict__ Wa1, const float* __restrict__ ba1,
    const float* __restrict__ Wa2, const float* __restrict__ ba2,
    float* __restrict__ aq1, float* __restrict__ aq2)
{
    __shared__ float afs[4][128];
    const int btBase = blockIdx.x * 4;
    const int tid = threadIdx.x;
    for (int i = tid; i < 512; i += 256) {
        int g = i >> 7, k = i & 127;
        int bt = btBase + g;
        int b = bt / 10, t = bt - b * 10;
        afs[g][k] = audio[(t * 256 + b) * 128 + k];
    }
    __syncthreads();
    const int c = tid;  // 0..255
    float a1a[4] = {0.f,0.f,0.f,0.f}, a1b[4] = {0.f,0.f,0.f,0.f}, a2[4] = {0.f,0.f,0.f,0.f};
    const float* w1a = Wa1 + c * 128;
    const float* w1b = Wa1 + (c + 256) * 128;
    const float* w2p = Wa2 + c * 128;
    for (int kk = 0; kk < 32; ++kk) {
        float4 va = *(const float4*)(w1a + kk * 4);
        float4 vb = *(const float4*)(w1b + kk * 4);
        float4 vc = *(const float4*)(w2p + kk * 4);
        float fa[4] = {va.x, va.y, va.z, va.w};
        float fb[4] = {vb.x, vb.y, vb.z, vb.w};
        float fc[4] = {vc.x, vc.y, vc.z, vc.w};
#pragma unroll
        for (int j = 0; j < 4; ++j) {
            int k = kk * 4 + j;
#pragma unroll
            for (int g = 0; g < 4; ++g) {
                float a = afs[g][k];
                a1a[g] += a * fa[j];
                a1b[g] += a * fb[j];
                a2[g]  += a * fc[j];
            }
        }
    }
    float b1a = ba1[c], b1b = ba1[c + 256], b2 = ba2[c];
#pragma unroll
    for (int g = 0; g < 4; ++g) {
        int bt = btBase + g;
        aq1[bt * 512 + c]       = fmaxf(a1a[g] + b1a, 0.f);
        aq1[bt * 512 + c + 256] = fmaxf(a1b[g] + b1b, 0.f);
        aq2[bt * 256 + c]       = fmaxf(a2[g] + b2, 0.f);
    }
}

// ---------------- Kernel 2: channel-attention GEMM.
// Grid: 1280 M-blocks (2 bt each, rows padded to 64) x 2 N-halves. 512 threads, 8 waves (2M x 4N).
// K tiled by 32, A+B double-buffered in LDS via async global_load_lds, 2-phase schedule.
// Epilogue: per-bt mean over 49 real rows of relu(.+bias), * aq1 -> avq.
__global__ __launch_bounds__(512) void k_chanatt_g(
    const unsigned short* __restrict__ videobf,
    const unsigned short* __restrict__ Wv1bf, const float* __restrict__ bv1,
    const float* __restrict__ aq1, float* __restrict__ avq)
{
    // per buffer: A 128x32 (4096 shorts) | B 256x32 (8192 shorts) = 12288 shorts
    __shared__ unsigned short lds[2 * 12288];
    const int tid = threadIdx.x;
    const int wave = tid >> 6, lane = tid & 63, quad = lane >> 4, l16 = lane & 15;
    const int wm = wave >> 2, wn = wave & 3;
    const int mb = blockIdx.x >> 1, nb = blockIdx.x & 1;
    const int bt0 = mb * 2;

    auto stage = [&](int buf, int kt) {
        const int base = buf * 12288;
        // A: 512 chunks of 16B (128 rows x 4 chunks), 1/thread
        {
            int row = tid >> 2, c = tid & 3;
            int hw = row & 63, btl = row >> 6;
            if (hw < 49) {
                async16(videobf + (size_t)(bt0 + btl) * 25088 + hw * 512
                                + kt * 32 + ((c ^ (row & 3)) << 3),
                        &lds[base + tid * 8]);
            }
        }
        // B: 1024 chunks (256 rows x 4 chunks), 2/thread
#pragma unroll
        for (int rep = 0; rep < 2; ++rep) {
            int q = tid + rep * 512;
            int row = q >> 2, c = q & 3;
            async16(Wv1bf + (size_t)((nb << 8) + row) * 512
                          + kt * 32 + ((c ^ (row & 3)) << 3),
                    &lds[base + 4096 + q * 8]);
        }
    };

    f32x4 acc[4][4];
#pragma unroll
    for (int mt = 0; mt < 4; ++mt)
#pragma unroll
        for (int nt = 0; nt < 4; ++nt)
            acc[mt][nt] = (f32x4){0.f, 0.f, 0.f, 0.f};

    stage(0, 0);
    __syncthreads();

    for (int kt = 0; kt < 16; ++kt) {
        int cur = kt & 1;
        if (kt < 15) stage(cur ^ 1, kt + 1);
        const int cb = cur * 12288;
        bf16x8 af[4];
#pragma unroll
        for (int mt = 0; mt < 4; ++mt) {
            int row = wm * 64 + mt * 16 + l16;
            af[mt] = *(const bf16x8*)&lds[cb + row * 32 + ((quad ^ (row & 3)) << 3)];
        }
#pragma unroll
        for (int nt = 0; nt < 4; ++nt) {
            int rowb = wn * 64 + nt * 16 + l16;
            bf16x8 bfr = *(const bf16x8*)&lds[cb + 4096 + rowb * 32 + ((quad ^ (rowb & 3)) << 3)];
#pragma unroll
            for (int mt = 0; mt < 4; ++mt)
                acc[mt][nt] = __builtin_amdgcn_mfma_f32_16x16x32_bf16(
                    af[mt], bfr, acc[mt][nt], 0, 0, 0);
        }
        __syncthreads();   // drains vmcnt -> next tile resident
    }

    // Epilogue: rows of bt = mt*16 + quad*4 + r; real iff < 49.
    const int bt = bt0 + wm;
#pragma unroll
    for (int nt = 0; nt < 4; ++nt) {
        int n = nb * 256 + wn * 64 + nt * 16 + l16;
        float bias = bv1[n];
        float s = 0.f;
#pragma unroll
        for (int mt = 0; mt < 4; ++mt)
#pragma unroll
            for (int r = 0; r < 4; ++r)
                if (mt < 3 || (quad == 0 && r == 0))   // rows 0..47 and row 48
                    s += fmaxf(acc[mt][nt][r] + bias, 0.f);
        s += __shfl_xor(s, 16, 64);
        s += __shfl_xor(s, 32, 64);
        if (quad == 0) {
            avq[bt * 512 + n] = aq1[bt * 512 + n] * (s * (1.f / 49.f));
        }
    }
}

// ---------------- Kernel 3: cmul = 1 + sigmoid( relu(avq@Wb^T+bb) @ Wc^T + bc )
__global__ __launch_bounds__(256) void k_mlp(
    const float* __restrict__ avq,
    const float* __restrict__ Wb, const float* __restrict__ bb,
    const float* __restrict__ Wc, const float* __restrict__ bc,
    float* __restrict__ cmul)
{
    __shared__ float av[4][512];
    __shared__ float hid[4][256];
    const int btBase = blockIdx.x * 4;
    const int tid = threadIdx.x;
    for (int i = tid; i < 2048; i += 256) {
        int g = i >> 9, c = i & 511;
        av[g][c] = avq[(btBase + g) * 512 + c];
    }
    __syncthreads();
    {
        float a[4] = {0.f,0.f,0.f,0.f};
        const float* wrow = Wb + tid * 512;
        for (int kk = 0; kk < 128; ++kk) {
            float4 v = *(const float4*)(wrow + kk * 4);
            float w[4] = {v.x, v.y, v.z, v.w};
#pragma unroll
            for (int j = 0; j < 4; ++j)
#pragma unroll
                for (int g = 0; g < 4; ++g)
                    a[g] += av[g][kk * 4 + j] * w[j];
        }
        float bias = bb[tid];
#pragma unroll
        for (int g = 0; g < 4; ++g) hid[g][tid] = fmaxf(a[g] + bias, 0.f);
    }
    __syncthreads();
#pragma unroll
    for (int rep = 0; rep < 2; ++rep) {
        int c = tid + rep * 256;
        float a[4] = {0.f,0.f,0.f,0.f};
        const float* wrow = Wc + c * 256;
        for (int kk = 0; kk < 64; ++kk) {
            float4 v = *(const float4*)(wrow + kk * 4);
            float w[4] = {v.x, v.y, v.z, v.w};
#pragma unroll
            for (int j = 0; j < 4; ++j)
#pragma unroll
                for (int g = 0; g < 4; ++g)
                    a[g] += hid[g][kk * 4 + j] * w[j];
        }
        float bias = bc[c];
#pragma unroll
        for (int g = 0; g < 4; ++g) {
            float s = 1.f / (1.f + __expf(-(a[g] + bias)));
            cmul[(btBase + g) * 512 + c] = 1.f + s;
        }
    }
}

// ---------------- Kernel 4: spatial GEMM + fused softmax weights.
// Grid: 1280 M-blocks (2 bt, padded 64). N=256 full. K tiled by 32.
// A = videobf * cmul (scaled during reg-staging; scale varies along K only).
// Epilogue: z[row] = sum_n relu(cq+bv2)*aq2*Ws, tanh, softmax over 49 -> smw[bt][64].
__global__ __launch_bounds__(512) void k_sgemm(
    const unsigned short* __restrict__ videobf,
    const float* __restrict__ cmul, const float* __restrict__ aq2,
    const unsigned short* __restrict__ Wv2bf, const float* __restrict__ bv2,
    const float* __restrict__ Wsp, const float* __restrict__ bsp,
    float* __restrict__ smw)
{
    __shared__ unsigned short lds[2 * 12288];   // A 4096 | B 8192 per buffer
    __shared__ float zsh[8][64];
    const int tid = threadIdx.x;
    const int wave = tid >> 6, lane = tid & 63, quad = lane >> 4, l16 = lane & 15;
    const int wm = wave >> 2, wn = wave & 3;
    const int bt0 = blockIdx.x * 2;

    auto stage = [&](int buf, int kt) {
        const int base = buf * 12288;
        // A: reg-staged (needs *cmul along K), 512 chunks, 1/thread
        {
            int row = tid >> 2, c = tid & 3;
            int hw = row & 63, btl = row >> 6;
            int bt = bt0 + btl;
            if (hw < 49) {
                int k0 = kt * 32 + ((c ^ (row & 3)) << 3);
                uint4 v = *(const uint4*)(videobf + (size_t)bt * 25088 + hw * 512 + k0);
                const float* cp = cmul + bt * 512 + k0;
                float4 c0 = *(const float4*)cp;
                float4 c1 = *(const float4*)(cp + 4);
                uint4 o;
                o.x = cvt_pk_bf16(bf2f_lo(v.x) * c0.x, bf2f_hi(v.x) * c0.y);
                o.y = cvt_pk_bf16(bf2f_lo(v.y) * c0.z, bf2f_hi(v.y) * c0.w);
                o.z = cvt_pk_bf16(bf2f_lo(v.z) * c1.x, bf2f_hi(v.z) * c1.y);
                o.w = cvt_pk_bf16(bf2f_lo(v.w) * c1.z, bf2f_hi(v.w) * c1.w);
                *(uint4*)&lds[base + tid * 8] = o;
            }
        }
        // B: async, 1024 chunks, 2/thread
#pragma unroll
        for (int rep = 0; rep < 2; ++rep) {
            int q = tid + rep * 512;
            int row = q >> 2, c = q & 3;
            async16(Wv2bf + (size_t)row * 512 + kt * 32 + ((c ^ (row & 3)) << 3),
                    &lds[base + 4096 + q * 8]);
        }
    };

    f32x4 acc[4][4];
#pragma unroll
    for (int mt = 0; mt < 4; ++mt)
#pragma unroll
        for (int nt = 0; nt < 4; ++nt)
            acc[mt][nt] = (f32x4){0.f, 0.f, 0.f, 0.f};

    stage(0, 0);
    __syncthreads();

    for (int kt = 0; kt < 16; ++kt) {
        int cur = kt & 1;
        if (kt < 15) stage(cur ^ 1, kt + 1);
        const int cb = cur * 12288;
        bf16x8 af[4];
#pragma unroll
        for (int mt = 0; mt < 4; ++mt) {
            int row = wm * 64 + mt * 16 + l16;
            af[mt] = *(const bf16x8*)&lds[cb + row * 32 + ((quad ^ (row & 3)) << 3)];
        }
#pragma unroll
        for (int nt = 0; nt < 4; ++nt) {
            int rowb = wn * 64 + nt * 16 + l16;
            bf16x8 bfr = *(const bf16x8*)&lds[cb + 4096 + rowb * 32 + ((quad ^ (rowb & 3)) << 3)];
#pragma unroll
            for (int mt = 0; mt < 4; ++mt)
                acc[mt][nt] = __builtin_amdgcn_mfma_f32_16x16x32_bf16(
                    af[mt], bfr, acc[mt][nt], 0, 0, 0);
        }
        __syncthreads();
    }

    // z-partials: zp[mt*4+r] = sum over this wave's 64 n of relu(acc+bias)*aq2*Ws
    const int bt = bt0 + wm;
    float zp[16];
#pragma unroll
    for (int i = 0; i < 16; ++i) zp[i] = 0.f;
#pragma unroll
    for (int nt = 0; nt < 4; ++nt) {
        int n = wn * 64 + nt * 16 + l16;
        float bias = bv2[n];
        float co = aq2[bt * 256 + n] * Wsp[n];
#pragma unroll
        for (int mt = 0; mt < 4; ++mt)
#pragma unroll
            for (int r = 0; r < 4; ++r)
                zp[mt * 4 + r] += fmaxf(acc[mt][nt][r] + bias, 0.f) * co;
    }
#pragma unroll
    for (int i = 0; i < 16; ++i) {
        float v = zp[i];
        v += __shfl_xor(v, 1, 64);
        v += __shfl_xor(v, 2, 64);
        v += __shfl_xor(v, 4, 64);
        v += __shfl_xor(v, 8, 64);
        zp[i] = v;
    }
    if (l16 == 0) {
#pragma unroll
        for (int mt = 0; mt < 4; ++mt)
#pragma unroll
            for (int r = 0; r < 4; ++r)
                zsh[wave][mt * 16 + quad * 4 + r] = zp[mt * 4 + r];
    }
    __syncthreads();

    if (wn == 0) {    // waves 0 (bt0) and 4 (bt0+1)
        int hw = lane;
        float z = zsh[wm * 4 + 0][hw] + zsh[wm * 4 + 1][hw]
                + zsh[wm * 4 + 2][hw] + zsh[wm * 4 + 3][hw] + bsp[0];
        float t = tanhf(z);
        float v = (hw < 49) ? t : -1e30f;
#pragma unroll
        for (int off = 32; off; off >>= 1) v = fmaxf(v, __shfl_xor(v, off, 64));
        float e = (hw < 49) ? __expf(t - v) : 0.f;
        float se = e;
#pragma unroll
        for (int off = 32; off; off >>= 1) se += __shfl_xor(se, off, 64);
        smw[bt * 64 + hw] = (hw < 49) ? (e / se) : 0.f;
    }
}

// ---------------- Kernel 5: out[bt,c] = cmul[bt,c] * sum_hw smw[bt,hw]*videobf[bt,hw,c]
__global__ __launch_bounds__(256) void k_out(
    const unsigned short* __restrict__ videobf,
    const float* __restrict__ cmul, const float* __restrict__ smw,
    float* __restrict__ out)
{
    __shared__ float sm[49];
    const int bt = blockIdx.x;
    const int tid = threadIdx.x;
    if (tid < 49) sm[tid] = smw[bt * 64 + tid];
    __syncthreads();
    const unsigned short* vsrc = videobf + (size_t)bt * 25088;
#pragma unroll
    for (int rep = 0; rep < 2; ++rep) {
        int c = tid + rep * 256;
        float m = cmul[bt * 512 + c];
        float s = 0.f;
        for (int hw = 0; hw < 49; ++hw)
            s += sm[hw] * bf2f(vsrc[hw * 512 + c]);
        out[bt * 512 + c] = s * m;
    }
}

// ================= Fallback kernels (original fp32-video path, used if ws too small) ======
__global__ __launch_bounds__(256) void k_chanatt_fb(
    const float* __restrict__ video,
    const unsigned short* __restrict__ Wv1bf, const float* __restrict__ bv1,
    const float* __restrict__ aq1, float* __restrict__ avq)
{
    __shared__ unsigned short At[49 * 512];
    const int bt = blockIdx.x;
    const int tid = threadIdx.x;
    const int wave = tid >> 6, lane = tid & 63, quad = lane >> 4, l16 = lane & 15;
    const float* vsrc = video + (size_t)bt * 25088;

    for (int c = tid; c < 3136; c += 256) {
        int row = c >> 6, ch = c & 63;
        float4 a = *(const float4*)(vsrc + row * 512 + ch * 8);
        float4 b = *(const float4*)(vsrc + row * 512 + ch * 8 + 4);
        float f[8] = {a.x, a.y, a.z, a.w, b.x, b.y, b.z, b.w};
        unsigned int o[8];
#pragma unroll
        for (int j = 0; j < 8; ++j) o[j] = f2bf(f[j]);
        uint4 pack;
        pack.x = o[0] | (o[1] << 16); pack.y = o[2] | (o[3] << 16);
        pack.z = o[4] | (o[5] << 16); pack.w = o[6] | (o[7] << 16);
        int chs = ch ^ (row & 7);
        *(uint4*)(&At[row * 512 + chs * 8]) = pack;
    }
    __syncthreads();

    f32x4 acc[4][8];
#pragma unroll
    for (int mt = 0; mt < 4; ++mt)
#pragma unroll
        for (int nt = 0; nt < 8; ++nt)
            acc[mt][nt] = (f32x4){0.f, 0.f, 0.f, 0.f};

    for (int kk = 0; kk < 16; ++kk) {
        int chunk = kk * 4 + quad;
        bf16x8 afrag[4];
#pragma unroll
        for (int mt = 0; mt < 4; ++mt) {
            int m = ((mt == 3) ? 33 : mt * 16) + l16;
            int chs = chunk ^ (m & 7);
            afrag[mt] = *(const bf16x8*)(&At[m * 512 + chs * 8]);
        }
        int koff = chunk * 8;
#pragma unroll
        for (int nt = 0; nt < 8; ++nt) {
            int n = (wave * 8 + nt) * 16 + l16;
            bf16x8 bfrag = *(const bf16x8*)(Wv1bf + n * 512 + koff);
#pragma unroll
            for (int mt = 0; mt < 4; ++mt)
                acc[mt][nt] = __builtin_amdgcn_mfma_f32_16x16x32_bf16(
                    afrag[mt], bfrag, acc[mt][nt], 0, 0, 0);
        }
    }

#pragma unroll
    for (int nt = 0; nt < 8; ++nt) {
        int n = (wave * 8 + nt) * 16 + l16;
        float bias = bv1[n];
        float s = 0.f;
#pragma unroll
        for (int mt = 0; mt < 4; ++mt)
#pragma unroll
            for (int r = 0; r < 4; ++r)
                if (mt < 3 || (quad == 3 && r == 3))
                    s += fmaxf(acc[mt][nt][r] + bias, 0.f);
        s += __shfl_xor(s, 16, 64);
        s += __shfl_xor(s, 32, 64);
        if (quad == 0) {
            float vm = s * (1.f / 49.f);
            avq[bt * 512 + n] = aq1[bt * 512 + n] * vm;
        }
    }
}

__global__ __launch_bounds__(256) void k_spatial_fb(
    const float* __restrict__ video,
    const float* __restrict__ cmul, const float* __restrict__ aq2,
    const unsigned short* __restrict__ Wv2bf, const float* __restrict__ bv2,
    const float* __restrict__ Wsp, const float* __restrict__ bsp,
    float* __restrict__ out)
{
    __shared__ unsigned short Ct[49 * 512];
    __shared__ float w2[256];
    __shared__ float zbuf[4][64];
    __shared__ float smwl[64];
    const int bt = blockIdx.x;
    const int tid = threadIdx.x;
    const int wave = tid >> 6, lane = tid & 63, quad = lane >> 4, l16 = lane & 15;
    const float* vsrc = video + (size_t)bt * 25088;
    const float* cm = cmul + bt * 512;

    for (int c = tid; c < 3136; c += 256) {
        int row = c >> 6, ch = c & 63;
        float4 a = *(const float4*)(vsrc + row * 512 + ch * 8);
        float4 b = *(const float4*)(vsrc + row * 512 + ch * 8 + 4);
        float f[8] = {a.x, a.y, a.z, a.w, b.x, b.y, b.z, b.w};
        float4 m0 = *(const float4*)(cm + ch * 8);
        float4 m1 = *(const float4*)(cm + ch * 8 + 4);
        float mm[8] = {m0.x, m0.y, m0.z, m0.w, m1.x, m1.y, m1.z, m1.w};
        unsigned int o[8];
#pragma unroll
        for (int j = 0; j < 8; ++j) o[j] = f2bf(f[j] * mm[j]);
        uint4 pack;
        pack.x = o[0] | (o[1] << 16); pack.y = o[2] | (o[3] << 16);
        pack.z = o[4] | (o[5] << 16); pack.w = o[6] | (o[7] << 16);
        int chs = ch ^ (row & 7);
        *(uint4*)(&Ct[row * 512 + chs * 8]) = pack;
    }
    w2[tid] = aq2[bt * 256 + tid] * Wsp[tid];
    if (lane >= 49) zbuf[wave][lane] = 0.f;
    __syncthreads();

    f32x4 acc[4][4];
#pragma unroll
    for (int mt = 0; mt < 4; ++mt)
#pragma unroll
        for (int nt = 0; nt < 4; ++nt)
            acc[mt][nt] = (f32x4){0.f, 0.f, 0.f, 0.f};

    for (int kk = 0; kk < 16; ++kk) {
        int chunk = kk * 4 + quad;
        bf16x8 afrag[4];
#pragma unroll
        for (int mt = 0; mt < 4; ++mt) {
            int m = ((mt == 3) ? 33 : mt * 16) + l16;
            int chs = chunk ^ (m & 7);
            afrag[mt] = *(const bf16x8*)(&Ct[m * 512 + chs * 8]);
        }
        int koff = chunk * 8;
#pragma unroll
        for (int nt = 0; nt < 4; ++nt) {
            int n = (wave * 4 + nt) * 16 + l16;
            bf16x8 bfrag = *(const bf16x8*)(Wv2bf + n * 512 + koff);
#pragma unroll
            for (int mt = 0; mt < 4; ++mt)
                acc[mt][nt] = __builtin_amdgcn_mfma_f32_16x16x32_bf16(
                    afrag[mt], bfrag, acc[mt][nt], 0, 0, 0);
        }
    }

    float zp[16];
#pragma unroll
    for (int i = 0; i < 16; ++i) zp[i] = 0.f;
#pragma unroll
    for (int nt = 0; nt < 4; ++nt) {
        int n = (wave * 4 + nt) * 16 + l16;
        float bias = bv2[n];
        float wnc = w2[n];
#pragma unroll
        for (int mt = 0; mt < 4; ++mt)
#pragma unroll
            for (int r = 0; r < 4; ++r)
                zp[mt * 4 + r] += fmaxf(acc[mt][nt][r] + bias, 0.f) * wnc;
    }
#pragma unroll
    for (int i = 0; i < 16; ++i) {
        float v = zp[i];
        v += __shfl_xor(v, 1, 64);
        v += __shfl_xor(v, 2, 64);
        v += __shfl_xor(v, 4, 64);
        v += __shfl_xor(v, 8, 64);
        zp[i] = v;
    }
    if (l16 == 0) {
#pragma unroll
        for (int mt = 0; mt < 4; ++mt)
#pragma unroll
            for (int r = 0; r < 4; ++r)
                if (mt < 3 || (quad == 3 && r == 3)) {
                    int row = ((mt == 3) ? 33 : mt * 16) + quad * 4 + r;
                    zbuf[wave][row] = zp[mt * 4 + r];
                }
    }
    __syncthreads();

    if (wave == 0) {
        int hw = lane;
        float z = zbuf[0][hw] + zbuf[1][hw] + zbuf[2][hw] + zbuf[3][hw] + bsp[0];
        float t = tanhf(z);
        float v = (hw < 49) ? t : -1e30f;
#pragma unroll
        for (int off = 32; off; off >>= 1) v = fmaxf(v, __shfl_xor(v, off, 64));
        float e = (hw < 49) ? __expf(t - v) : 0.f;
        float se = e;
#pragma unroll
        for (int off = 32; off; off >>= 1) se += __shfl_xor(se, off, 64);
        smwl[hw] = e / se;
    }
    __syncthreads();

#pragma unroll
    for (int rep = 0; rep < 2; ++rep) {
        int cidx = tid + rep * 256;
        int chb = cidx >> 3, jj = cidx & 7;
        float s = 0.f;
        for (int hw = 0; hw < 49; ++hw) {
            int chs = chb ^ (hw & 7);
            s += smwl[hw] * bf2f(Ct[hw * 512 + chs * 8 + jj]);
        }
        out[bt * 512 + cidx] = s;
    }
}

extern "C" void kernel_launch(void* const* d_in, const int* in_sizes, int n_in,
                              void* d_out, int out_size, void* d_ws, size_t ws_size,
                              hipStream_t stream) {
    const float* video = (const float*)d_in[0];
    const float* audio = (const float*)d_in[1];
    const float* Wv1 = (const float*)d_in[2];
    const float* bv1 = (const float*)d_in[3];
    const float* Wa1 = (const float*)d_in[4];
    const float* ba1 = (const float*)d_in[5];
    const float* Wb  = (const float*)d_in[6];
    const float* bb  = (const float*)d_in[7];
    const float* Wc  = (const float*)d_in[8];
    const float* bc  = (const float*)d_in[9];
    const float* Wv2 = (const float*)d_in[10];
    const float* bv2 = (const float*)d_in[11];
    const float* Wa2 = (const float*)d_in[12];
    const float* ba2 = (const float*)d_in[13];
    const float* Wsp = (const float*)d_in[14];
    const float* bsp = (const float*)d_in[15];
    float* out = (float*)d_out;

    // new path: videobf 128,450,560 + Wv1bf 524,288 + Wv2bf 262,144
    //           + 4 f32 arrays 18,350,080 = 147,587,072 bytes (smw aliases aq1)
    const size_t NEED = 147587072u;
    if (ws_size >= NEED) {
        unsigned short* videobf = (unsigned short*)d_ws;        // 64,225,280 shorts
        unsigned short* Wv1bf = videobf + 64225280;             // 262,144
        unsigned short* Wv2bf = Wv1bf + 262144;                 // 131,072
        float* fbase = (float*)(Wv2bf + 131072);
        float* aq1  = fbase;                    // [2560,512]  (later reused as smw [2560,64])
        float* aq2  = aq1 + 1310720;            // [2560,256]
        float* avq  = aq2 + 655360;             // [2560,512]
        float* cmul = avq + 1310720;            // [2560,512]
        float* smw  = aq1;                      // alias: aq1 dead after k_chanatt_g

        k_prep<<<1536, 256, 0, stream>>>(Wv1, Wv2, Wv1bf, Wv2bf);
        k_prepv<<<4096, 256, 0, stream>>>(video, videobf);
        k_audio<<<640, 256, 0, stream>>>(audio, Wa1, ba1, Wa2, ba2, aq1, aq2);
        k_chanatt_g<<<2560, 512, 0, stream>>>(videobf, Wv1bf, bv1, aq1, avq);
        k_mlp<<<640, 256, 0, stream>>>(avq, Wb, bb, Wc, bc, cmul);
        k_sgemm<<<1280, 512, 0, stream>>>(videobf, cmul, aq2, Wv2bf, bv2, Wsp, bsp, smw);
        k_out<<<2560, 256, 0, stream>>>(videobf, cmul, smw, out);
    } else {
        float* ws = (float*)d_ws;
        float* aq1  = ws;                       // [2560,512]
        float* aq2  = aq1 + 1310720;            // [2560,256]
        float* avq  = aq2 + 655360;             // [2560,512]
        float* cmul = avq + 1310720;            // [2560,512]
        unsigned short* Wv1bf = (unsigned short*)(cmul + 1310720);  // 512x512
        unsigned short* Wv2bf = Wv1bf + 262144;                     // 256x512

        k_prep<<<1536, 256, 0, stream>>>(Wv1, Wv2, Wv1bf, Wv2bf);
        k_audio<<<640, 256, 0, stream>>>(audio, Wa1, ba1, Wa2, ba2, aq1, aq2);
        k_chanatt_fb<<<2560, 256, 0, stream>>>(video, Wv1bf, bv1, aq1, avq);
        k_mlp<<<640, 256, 0, stream>>>(avq, Wb, bb, Wc, bc, cmul);
        k_spatial_fb<<<2560, 256, 0, stream>>>(video, cmul, aq2, Wv2bf, bv2, Wsp, bsp, out);
    }
}

// Round 4
// 739.545 us; speedup vs baseline: 1.2288x; 1.0235x over previous
//
#include <hip/hip_runtime.h>

typedef __bf16 bf16x8 __attribute__((ext_vector_type(8)));
typedef float f32x4 __attribute__((ext_vector_type(4)));

__device__ __forceinline__ unsigned short f2bf(float f) {
    union { float f; unsigned int u; } x; x.f = f;
    unsigned int r = x.u + 0x7FFFu + ((x.u >> 16) & 1u);
    return (unsigned short)(r >> 16);
}
__device__ __forceinline__ float bf2f(unsigned short v) {
    union { unsigned int u; float f; } x; x.u = ((unsigned int)v) << 16; return x.f;
}
__device__ __forceinline__ float bf2f_lo(unsigned int w) {
    union { unsigned int u; float f; } x; x.u = w << 16; return x.f;
}
__device__ __forceinline__ float bf2f_hi(unsigned int w) {
    union { unsigned int u; float f; } x; x.u = w & 0xffff0000u; return x.f;
}
__device__ __forceinline__ unsigned int cvt_pk_bf16(float lo, float hi) {
    unsigned int r;
    asm("v_cvt_pk_bf16_f32 %0, %1, %2" : "=v"(r) : "v"(lo), "v"(hi));
    return r;
}
// async global->LDS, 16B per lane. LDS dest must be lane-linear within a wave.
__device__ __forceinline__ void async16(const void* g, void* l) {
    __builtin_amdgcn_global_load_lds(
        (const __attribute__((address_space(1))) unsigned int*)g,
        (__attribute__((address_space(3))) unsigned int*)l, 16, 0, 0);
}

// ---------------- k_front: fused {video fp32->bf16, Wv1/Wv2 fp32->bf16, audio MLP}.
// blocks [0,4096): prepv; [4096,4480): weight convert; [4480,5120): audio.
__global__ __launch_bounds__(256) void k_front(
    const float* __restrict__ video, unsigned short* __restrict__ vbf,
    const float* __restrict__ Wv1, const float* __restrict__ Wv2,
    unsigned short* __restrict__ Wv1bf, unsigned short* __restrict__ Wv2bf,
    const float* __restrict__ audio,
    const float* __restrict__ Wa1, const float* __restrict__ ba1,
    const float* __restrict__ Wa2, const float* __restrict__ ba2,
    float* __restrict__ aq1, float* __restrict__ aq2)
{
    const int b = blockIdx.x;
    const int tid = threadIdx.x;
    if (b < 4096) {
        // video convert: 8,028,160 chunks of 8 elems
        const size_t stride = (size_t)4096 * 256;
        for (size_t c = (size_t)b * 256 + tid; c < 8028160u; c += stride) {
            const float* p = video + c * 8;
            float4 a = *(const float4*)p;
            float4 bb4 = *(const float4*)(p + 4);
            uint4 o;
            o.x = cvt_pk_bf16(a.x, a.y); o.y = cvt_pk_bf16(a.z, a.w);
            o.z = cvt_pk_bf16(bb4.x, bb4.y); o.w = cvt_pk_bf16(bb4.z, bb4.w);
            *(uint4*)(vbf + c * 8) = o;
        }
        return;
    }
    if (b < 4480) {
        // weights: 393,216 elems, 1024 per block
        int base = (b - 4096) * 1024 + tid;
#pragma unroll
        for (int r = 0; r < 4; ++r) {
            int idx = base + r * 256;
            if (idx < 262144) Wv1bf[idx] = f2bf(Wv1[idx]);
            else              Wv2bf[idx - 262144] = f2bf(Wv2[idx - 262144]);
        }
        return;
    }
    // audio: aq1 = relu(af@Wa1^T+ba1), aq2 = relu(af@Wa2^T+ba2)
    __shared__ float afs[4][128];
    const int btBase = (b - 4480) * 4;
    for (int i = tid; i < 512; i += 256) {
        int g = i >> 7, k = i & 127;
        int bt = btBase + g;
        int bb_ = bt / 10, t = bt - bb_ * 10;
        afs[g][k] = audio[(t * 256 + bb_) * 128 + k];
    }
    __syncthreads();
    const int c = tid;
    float a1a[4] = {0.f,0.f,0.f,0.f}, a1b[4] = {0.f,0.f,0.f,0.f}, a2[4] = {0.f,0.f,0.f,0.f};
    const float* w1a = Wa1 + c * 128;
    const float* w1b = Wa1 + (c + 256) * 128;
    const float* w2p = Wa2 + c * 128;
    for (int kk = 0; kk < 32; ++kk) {
        float4 va = *(const float4*)(w1a + kk * 4);
        float4 vb = *(const float4*)(w1b + kk * 4);
        float4 vc = *(const float4*)(w2p + kk * 4);
        float fa[4] = {va.x, va.y, va.z, va.w};
        float fb[4] = {vb.x, vb.y, vb.z, vb.w};
        float fc[4] = {vc.x, vc.y, vc.z, vc.w};
#pragma unroll
        for (int j = 0; j < 4; ++j) {
            int k = kk * 4 + j;
#pragma unroll
            for (int g = 0; g < 4; ++g) {
                float a = afs[g][k];
                a1a[g] += a * fa[j];
                a1b[g] += a * fb[j];
                a2[g]  += a * fc[j];
            }
        }
    }
    float b1a = ba1[c], b1b = ba1[c + 256], b2 = ba2[c];
#pragma unroll
    for (int g = 0; g < 4; ++g) {
        int bt = btBase + g;
        aq1[bt * 512 + c]       = fmaxf(a1a[g] + b1a, 0.f);
        aq1[bt * 512 + c + 256] = fmaxf(a1b[g] + b1b, 0.f);
        aq2[bt * 256 + c]       = fmaxf(a2[g] + b2, 0.f);
    }
}

// ---------------- Kernel 2: channel-attention GEMM (unchanged structure).
__global__ __launch_bounds__(512) void k_chanatt_g(
    const unsigned short* __restrict__ videobf,
    const unsigned short* __restrict__ Wv1bf, const float* __restrict__ bv1,
    const float* __restrict__ aq1, float* __restrict__ avq)
{
    // per buffer: A 128x32 (4096 shorts) | B 256x32 (8192 shorts) = 12288 shorts
    __shared__ unsigned short lds[2 * 12288];
    const int tid = threadIdx.x;
    const int wave = tid >> 6, lane = tid & 63, quad = lane >> 4, l16 = lane & 15;
    const int wm = wave >> 2, wn = wave & 3;
    const int mb = blockIdx.x >> 1, nb = blockIdx.x & 1;
    const int bt0 = mb * 2;

    auto stage = [&](int buf, int kt) {
        const int base = buf * 12288;
        {
            int row = tid >> 2, c = tid & 3;
            int hw = row & 63, btl = row >> 6;
            if (hw < 49) {
                async16(videobf + (size_t)(bt0 + btl) * 25088 + hw * 512
                                + kt * 32 + ((c ^ (row & 3)) << 3),
                        &lds[base + tid * 8]);
            }
        }
#pragma unroll
        for (int rep = 0; rep < 2; ++rep) {
            int q = tid + rep * 512;
            int row = q >> 2, c = q & 3;
            async16(Wv1bf + (size_t)((nb << 8) + row) * 512
                          + kt * 32 + ((c ^ (row & 3)) << 3),
                    &lds[base + 4096 + q * 8]);
        }
    };

    f32x4 acc[4][4];
#pragma unroll
    for (int mt = 0; mt < 4; ++mt)
#pragma unroll
        for (int nt = 0; nt < 4; ++nt)
            acc[mt][nt] = (f32x4){0.f, 0.f, 0.f, 0.f};

    stage(0, 0);
    __syncthreads();

    for (int kt = 0; kt < 16; ++kt) {
        int cur = kt & 1;
        if (kt < 15) stage(cur ^ 1, kt + 1);
        const int cb = cur * 12288;
        bf16x8 af[4];
#pragma unroll
        for (int mt = 0; mt < 4; ++mt) {
            int row = wm * 64 + mt * 16 + l16;
            af[mt] = *(const bf16x8*)&lds[cb + row * 32 + ((quad ^ (row & 3)) << 3)];
        }
#pragma unroll
        for (int nt = 0; nt < 4; ++nt) {
            int rowb = wn * 64 + nt * 16 + l16;
            bf16x8 bfr = *(const bf16x8*)&lds[cb + 4096 + rowb * 32 + ((quad ^ (rowb & 3)) << 3)];
#pragma unroll
            for (int mt = 0; mt < 4; ++mt)
                acc[mt][nt] = __builtin_amdgcn_mfma_f32_16x16x32_bf16(
                    af[mt], bfr, acc[mt][nt], 0, 0, 0);
        }
        __syncthreads();
    }

    const int bt = bt0 + wm;
#pragma unroll
    for (int nt = 0; nt < 4; ++nt) {
        int n = nb * 256 + wn * 64 + nt * 16 + l16;
        float bias = bv1[n];
        float s = 0.f;
#pragma unroll
        for (int mt = 0; mt < 4; ++mt)
#pragma unroll
            for (int r = 0; r < 4; ++r)
                if (mt < 3 || (quad == 0 && r == 0))   // rows 0..47 and row 48
                    s += fmaxf(acc[mt][nt][r] + bias, 0.f);
        s += __shfl_xor(s, 16, 64);
        s += __shfl_xor(s, 32, 64);
        if (quad == 0) {
            avq[bt * 512 + n] = aq1[bt * 512 + n] * (s * (1.f / 49.f));
        }
    }
}

// ---------------- Kernel 3: cmul = 1 + sigmoid( relu(avq@Wb^T+bb) @ Wc^T + bc )
__global__ __launch_bounds__(256) void k_mlp(
    const float* __restrict__ avq,
    const float* __restrict__ Wb, const float* __restrict__ bb,
    const float* __restrict__ Wc, const float* __restrict__ bc,
    float* __restrict__ cmul)
{
    __shared__ float av[4][512];
    __shared__ float hid[4][256];
    const int btBase = blockIdx.x * 4;
    const int tid = threadIdx.x;
    for (int i = tid; i < 2048; i += 256) {
        int g = i >> 9, c = i & 511;
        av[g][c] = avq[(btBase + g) * 512 + c];
    }
    __syncthreads();
    {
        float a[4] = {0.f,0.f,0.f,0.f};
        const float* wrow = Wb + tid * 512;
        for (int kk = 0; kk < 128; ++kk) {
            float4 v = *(const float4*)(wrow + kk * 4);
            float w[4] = {v.x, v.y, v.z, v.w};
#pragma unroll
            for (int j = 0; j < 4; ++j)
#pragma unroll
                for (int g = 0; g < 4; ++g)
                    a[g] += av[g][kk * 4 + j] * w[j];
        }
        float bias = bb[tid];
#pragma unroll
        for (int g = 0; g < 4; ++g) hid[g][tid] = fmaxf(a[g] + bias, 0.f);
    }
    __syncthreads();
#pragma unroll
    for (int rep = 0; rep < 2; ++rep) {
        int c = tid + rep * 256;
        float a[4] = {0.f,0.f,0.f,0.f};
        const float* wrow = Wc + c * 256;
        for (int kk = 0; kk < 64; ++kk) {
            float4 v = *(const float4*)(wrow + kk * 4);
            float w[4] = {v.x, v.y, v.z, v.w};
#pragma unroll
            for (int j = 0; j < 4; ++j)
#pragma unroll
                for (int g = 0; g < 4; ++g)
                    a[g] += hid[g][kk * 4 + j] * w[j];
        }
        float bias = bc[c];
#pragma unroll
        for (int g = 0; g < 4; ++g) {
            float s = 1.f / (1.f + __expf(-(a[g] + bias)));
            cmul[(btBase + g) * 512 + c] = 1.f + s;
        }
    }
}

// ---------------- Kernel 4: spatial GEMM + softmax + fused output contraction.
// Grid: 1280 blocks (2 bt, rows padded to 64). 512 threads, 8 waves (2M x 4N).
// A = videobf*cmul, T14-split reg staging (issue-early / write-late). B async in LDS.
// Tail: smw kept in LDS; out[bt,c] = cmul[bt,c]*sum_hw smw[hw]*videobf[bt,hw,c].
__global__ __launch_bounds__(512) void k_sgemm(
    const unsigned short* __restrict__ videobf,
    const float* __restrict__ cmul, const float* __restrict__ aq2,
    const unsigned short* __restrict__ Wv2bf, const float* __restrict__ bv2,
    const float* __restrict__ Wsp, const float* __restrict__ bsp,
    float* __restrict__ out)
{
    __shared__ unsigned short lds[2 * 12288];   // A 4096 | B 8192 per buffer
    __shared__ float zsh[8][64];
    __shared__ float smloc[2][64];
    const int tid = threadIdx.x;
    const int wave = tid >> 6, lane = tid & 63, quad = lane >> 4, l16 = lane & 15;
    const int wm = wave >> 2, wn = wave & 3;
    const int bt0 = blockIdx.x * 2;

    // ---- A staging state (T14 split) ----
    const int arow = tid >> 2, ac = tid & 3;
    const int ahw = arow & 63, abtl = arow >> 6;
    const bool aok = (ahw < 49);
    const int aswz = (ac ^ (arow & 3)) << 3;
    const unsigned short* avsrc = videobf + (size_t)(bt0 + abtl) * 25088 + ahw * 512;
    const float* acm = cmul + (bt0 + abtl) * 512;
    uint4 vreg;
    float4 c0reg, c1reg;

    auto aload = [&](int kt) {
        if (aok) {
            int k0 = kt * 32 + aswz;
            vreg  = *(const uint4*)(avsrc + k0);
            c0reg = *(const float4*)(acm + k0);
            c1reg = *(const float4*)(acm + k0 + 4);
        }
    };
    auto awrite = [&](int buf) {
        if (aok) {
            uint4 o;
            o.x = cvt_pk_bf16(bf2f_lo(vreg.x) * c0reg.x, bf2f_hi(vreg.x) * c0reg.y);
            o.y = cvt_pk_bf16(bf2f_lo(vreg.y) * c0reg.z, bf2f_hi(vreg.y) * c0reg.w);
            o.z = cvt_pk_bf16(bf2f_lo(vreg.z) * c1reg.x, bf2f_hi(vreg.z) * c1reg.y);
            o.w = cvt_pk_bf16(bf2f_lo(vreg.w) * c1reg.z, bf2f_hi(vreg.w) * c1reg.w);
            *(uint4*)&lds[buf * 12288 + tid * 8] = o;
        }
    };
    auto stageB = [&](int buf, int kt) {
#pragma unroll
        for (int rep = 0; rep < 2; ++rep) {
            int q = tid + rep * 512;
            int row = q >> 2, c = q & 3;
            async16(Wv2bf + (size_t)row * 512 + kt * 32 + ((c ^ (row & 3)) << 3),
                    &lds[buf * 12288 + 4096 + q * 8]);
        }
    };

    f32x4 acc[4][4];
#pragma unroll
    for (int mt = 0; mt < 4; ++mt)
#pragma unroll
        for (int nt = 0; nt < 4; ++nt)
            acc[mt][nt] = (f32x4){0.f, 0.f, 0.f, 0.f};

    aload(0);
    stageB(0, 0);
    awrite(0);
    __syncthreads();

    for (int kt = 0; kt < 16; ++kt) {
        int cur = kt & 1;
        if (kt < 15) { aload(kt + 1); stageB(cur ^ 1, kt + 1); }
        const int cb = cur * 12288;
        bf16x8 af[4];
#pragma unroll
        for (int mt = 0; mt < 4; ++mt) {
            int row = wm * 64 + mt * 16 + l16;
            af[mt] = *(const bf16x8*)&lds[cb + row * 32 + ((quad ^ (row & 3)) << 3)];
        }
#pragma unroll
        for (int nt = 0; nt < 4; ++nt) {
            int rowb = wn * 64 + nt * 16 + l16;
            bf16x8 bfr = *(const bf16x8*)&lds[cb + 4096 + rowb * 32 + ((quad ^ (rowb & 3)) << 3)];
#pragma unroll
            for (int mt = 0; mt < 4; ++mt)
                acc[mt][nt] = __builtin_amdgcn_mfma_f32_16x16x32_bf16(
                    af[mt], bfr, acc[mt][nt], 0, 0, 0);
        }
        if (kt < 15) awrite(cur ^ 1);
        __syncthreads();
    }

    // z-partials
    const int bt = bt0 + wm;
    float zp[16];
#pragma unroll
    for (int i = 0; i < 16; ++i) zp[i] = 0.f;
#pragma unroll
    for (int nt = 0; nt < 4; ++nt) {
        int n = wn * 64 + nt * 16 + l16;
        float bias = bv2[n];
        float co = aq2[bt * 256 + n] * Wsp[n];
#pragma unroll
        for (int mt = 0; mt < 4; ++mt)
#pragma unroll
            for (int r = 0; r < 4; ++r)
                zp[mt * 4 + r] += fmaxf(acc[mt][nt][r] + bias, 0.f) * co;
    }
#pragma unroll
    for (int i = 0; i < 16; ++i) {
        float v = zp[i];
        v += __shfl_xor(v, 1, 64);
        v += __shfl_xor(v, 2, 64);
        v += __shfl_xor(v, 4, 64);
        v += __shfl_xor(v, 8, 64);
        zp[i] = v;
    }
    if (l16 == 0) {
#pragma unroll
        for (int mt = 0; mt < 4; ++mt)
#pragma unroll
            for (int r = 0; r < 4; ++r)
                zsh[wave][mt * 16 + quad * 4 + r] = zp[mt * 4 + r];
    }
    __syncthreads();

    if (wn == 0) {    // waves 0 (bt0) and 4 (bt0+1)
        int hw = lane;
        float z = zsh[wm * 4 + 0][hw] + zsh[wm * 4 + 1][hw]
                + zsh[wm * 4 + 2][hw] + zsh[wm * 4 + 3][hw] + bsp[0];
        float t = tanhf(z);
        float v = (hw < 49) ? t : -1e30f;
#pragma unroll
        for (int off = 32; off; off >>= 1) v = fmaxf(v, __shfl_xor(v, off, 64));
        float e = (hw < 49) ? __expf(t - v) : 0.f;
        float se = e;
#pragma unroll
        for (int off = 32; off; off >>= 1) se += __shfl_xor(se, off, 64);
        smloc[wm][hw] = (hw < 49) ? (e / se) : 0.f;
    }
    __syncthreads();

    // fused output: group g (btl, 8-channel chunk), 4 threads split hw
    {
        int g = tid >> 2, part = tid & 3;
        int btl = g >> 6, cg = g & 63;
        const unsigned short* vs = videobf + (size_t)(bt0 + btl) * 25088 + cg * 8;
        float s[8];
#pragma unroll
        for (int j = 0; j < 8; ++j) s[j] = 0.f;
        for (int hw = part; hw < 49; hw += 4) {
            float w = smloc[btl][hw];
            uint4 v = *(const uint4*)(vs + hw * 512);
            s[0] += w * bf2f_lo(v.x); s[1] += w * bf2f_hi(v.x);
            s[2] += w * bf2f_lo(v.y); s[3] += w * bf2f_hi(v.y);
            s[4] += w * bf2f_lo(v.z); s[5] += w * bf2f_hi(v.z);
            s[6] += w * bf2f_lo(v.w); s[7] += w * bf2f_hi(v.w);
        }
#pragma unroll
        for (int j = 0; j < 8; ++j) {
            s[j] += __shfl_xor(s[j], 1, 64);
            s[j] += __shfl_xor(s[j], 2, 64);
        }
        if (part == 0) {
            const float* cm = cmul + (bt0 + btl) * 512 + cg * 8;
            float4 m0 = *(const float4*)cm;
            float4 m1 = *(const float4*)(cm + 4);
            float mm[8] = {m0.x, m0.y, m0.z, m0.w, m1.x, m1.y, m1.z, m1.w};
            float* op = out + (bt0 + btl) * 512 + cg * 8;
#pragma unroll
            for (int j = 0; j < 8; ++j) op[j] = s[j] * mm[j];
        }
    }
}

// ================= Fallback path (fp32 video, known-good) =================
__global__ __launch_bounds__(256) void k_prep(
    const float* __restrict__ Wv1, const float* __restrict__ Wv2,
    unsigned short* __restrict__ Wv1bf, unsigned short* __restrict__ Wv2bf)
{
    int idx = blockIdx.x * 256 + threadIdx.x;
    if (idx < 262144) {
        Wv1bf[idx] = f2bf(Wv1[idx]);
    } else {
        int j = idx - 262144;
        Wv2bf[j] = f2bf(Wv2[j]);
    }
}

__global__ __launch_bounds__(256) void k_audio(
    const float* __restrict__ audio,
    const float* __restrict__ Wa1, const float* __restrict__ ba1,
    const float* __restrict__ Wa2, const float* __restrict__ ba2,
    float* __restrict__ aq1, float* __restrict__ aq2)
{
    __shared__ float afs[4][128];
    const int btBase = blockIdx.x * 4;
    const int tid = threadIdx.x;
    for (int i = tid; i < 512; i += 256) {
        int g = i >> 7, k = i & 127;
        int bt = btBase + g;
        int b = bt / 10, t = bt - b * 10;
        afs[g][k] = audio[(t * 256 + b) * 128 + k];
    }
    __syncthreads();
    const int c = tid;
    float a1a[4] = {0.f,0.f,0.f,0.f}, a1b[4] = {0.f,0.f,0.f,0.f}, a2[4] = {0.f,0.f,0.f,0.f};
    const float* w1a = Wa1 + c * 128;
    const float* w1b = Wa1 + (c + 256) * 128;
    const float* w2p = Wa2 + c * 128;
    for (int kk = 0; kk < 32; ++kk) {
        float4 va = *(const float4*)(w1a + kk * 4);
        float4 vb = *(const float4*)(w1b + kk * 4);
        float4 vc = *(const float4*)(w2p + kk * 4);
        float fa[4] = {va.x, va.y, va.z, va.w};
        float fb[4] = {vb.x, vb.y, vb.z, vb.w};
        float fc[4] = {vc.x, vc.y, vc.z, vc.w};
#pragma unroll
        for (int j = 0; j < 4; ++j) {
            int k = kk * 4 + j;
#pragma unroll
            for (int g = 0; g < 4; ++g) {
                float a = afs[g][k];
                a1a[g] += a * fa[j];
                a1b[g] += a * fb[j];
                a2[g]  += a * fc[j];
            }
        }
    }
    float b1a = ba1[c], b1b = ba1[c + 256], b2 = ba2[c];
#pragma unroll
    for (int g = 0; g < 4; ++g) {
        int bt = btBase + g;
        aq1[bt * 512 + c]       = fmaxf(a1a[g] + b1a, 0.f);
        aq1[bt * 512 + c + 256] = fmaxf(a1b[g] + b1b, 0.f);
        aq2[bt * 256 + c]       = fmaxf(a2[g] + b2, 0.f);
    }
}

__global__ __launch_bounds__(256) void k_chanatt_fb(
    const float* __restrict__ video,
    const unsigned short* __restrict__ Wv1bf, const float* __restrict__ bv1,
    const float* __restrict__ aq1, float* __restrict__ avq)
{
    __shared__ unsigned short At[49 * 512];
    const int bt = blockIdx.x;
    const int tid = threadIdx.x;
    const int wave = tid >> 6, lane = tid & 63, quad = lane >> 4, l16 = lane & 15;
    const float* vsrc = video + (size_t)bt * 25088;

    for (int c = tid; c < 3136; c += 256) {
        int row = c >> 6, ch = c & 63;
        float4 a = *(const float4*)(vsrc + row * 512 + ch * 8);
        float4 b = *(const float4*)(vsrc + row * 512 + ch * 8 + 4);
        float f[8] = {a.x, a.y, a.z, a.w, b.x, b.y, b.z, b.w};
        unsigned int o[8];
#pragma unroll
        for (int j = 0; j < 8; ++j) o[j] = f2bf(f[j]);
        uint4 pack;
        pack.x = o[0] | (o[1] << 16); pack.y = o[2] | (o[3] << 16);
        pack.z = o[4] | (o[5] << 16); pack.w = o[6] | (o[7] << 16);
        int chs = ch ^ (row & 7);
        *(uint4*)(&At[row * 512 + chs * 8]) = pack;
    }
    __syncthreads();

    f32x4 acc[4][8];
#pragma unroll
    for (int mt = 0; mt < 4; ++mt)
#pragma unroll
        for (int nt = 0; nt < 8; ++nt)
            acc[mt][nt] = (f32x4){0.f, 0.f, 0.f, 0.f};

    for (int kk = 0; kk < 16; ++kk) {
        int chunk = kk * 4 + quad;
        bf16x8 afrag[4];
#pragma unroll
        for (int mt = 0; mt < 4; ++mt) {
            int m = ((mt == 3) ? 33 : mt * 16) + l16;
            int chs = chunk ^ (m & 7);
            afrag[mt] = *(const bf16x8*)(&At[m * 512 + chs * 8]);
        }
        int koff = chunk * 8;
#pragma unroll
        for (int nt = 0; nt < 8; ++nt) {
            int n = (wave * 8 + nt) * 16 + l16;
            bf16x8 bfrag = *(const bf16x8*)(Wv1bf + n * 512 + koff);
#pragma unroll
            for (int mt = 0; mt < 4; ++mt)
                acc[mt][nt] = __builtin_amdgcn_mfma_f32_16x16x32_bf16(
                    afrag[mt], bfrag, acc[mt][nt], 0, 0, 0);
        }
    }

#pragma unroll
    for (int nt = 0; nt < 8; ++nt) {
        int n = (wave * 8 + nt) * 16 + l16;
        float bias = bv1[n];
        float s = 0.f;
#pragma unroll
        for (int mt = 0; mt < 4; ++mt)
#pragma unroll
            for (int r = 0; r < 4; ++r)
                if (mt < 3 || (quad == 3 && r == 3))
                    s += fmaxf(acc[mt][nt][r] + bias, 0.f);
        s += __shfl_xor(s, 16, 64);
        s += __shfl_xor(s, 32, 64);
        if (quad == 0) {
            float vm = s * (1.f / 49.f);
            avq[bt * 512 + n] = aq1[bt * 512 + n] * vm;
        }
    }
}

__global__ __launch_bounds__(256) void k_spatial_fb(
    const float* __restrict__ video,
    const float* __restrict__ cmul, const float* __restrict__ aq2,
    const unsigned short* __restrict__ Wv2bf, const float* __restrict__ bv2,
    const float* __restrict__ Wsp, const float* __restrict__ bsp,
    float* __restrict__ out)
{
    __shared__ unsigned short Ct[49 * 512];
    __shared__ float w2[256];
    __shared__ float zbuf[4][64];
    __shared__ float smwl[64];
    const int bt = blockIdx.x;
    const int tid = threadIdx.x;
    const int wave = tid >> 6, lane = tid & 63, quad = lane >> 4, l16 = lane & 15;
    const float* vsrc = video + (size_t)bt * 25088;
    const float* cm = cmul + bt * 512;

    for (int c = tid; c < 3136; c += 256) {
        int row = c >> 6, ch = c & 63;
        float4 a = *(const float4*)(vsrc + row * 512 + ch * 8);
        float4 b = *(const float4*)(vsrc + row * 512 + ch * 8 + 4);
        float f[8] = {a.x, a.y, a.z, a.w, b.x, b.y, b.z, b.w};
        float4 m0 = *(const float4*)(cm + ch * 8);
        float4 m1 = *(const float4*)(cm + ch * 8 + 4);
        float mm[8] = {m0.x, m0.y, m0.z, m0.w, m1.x, m1.y, m1.z, m1.w};
        unsigned int o[8];
#pragma unroll
        for (int j = 0; j < 8; ++j) o[j] = f2bf(f[j] * mm[j]);
        uint4 pack;
        pack.x = o[0] | (o[1] << 16); pack.y = o[2] | (o[3] << 16);
        pack.z = o[4] | (o[5] << 16); pack.w = o[6] | (o[7] << 16);
        int chs = ch ^ (row & 7);
        *(uint4*)(&Ct[row * 512 + chs * 8]) = pack;
    }
    w2[tid] = aq2[bt * 256 + tid] * Wsp[tid];
    if (lane >= 49) zbuf[wave][lane] = 0.f;
    __syncthreads();

    f32x4 acc[4][4];
#pragma unroll
    for (int mt = 0; mt < 4; ++mt)
#pragma unroll
        for (int nt = 0; nt < 4; ++nt)
            acc[mt][nt] = (f32x4){0.f, 0.f, 0.f, 0.f};

    for (int kk = 0; kk < 16; ++kk) {
        int chunk = kk * 4 + quad;
        bf16x8 afrag[4];
#pragma unroll
        for (int mt = 0; mt < 4; ++mt) {
            int m = ((mt == 3) ? 33 : mt * 16) + l16;
            int chs = chunk ^ (m & 7);
            afrag[mt] = *(const bf16x8*)(&Ct[m * 512 + chs * 8]);
        }
        int koff = chunk * 8;
#pragma unroll
        for (int nt = 0; nt < 4; ++nt) {
            int n = (wave * 4 + nt) * 16 + l16;
            bf16x8 bfrag = *(const bf16x8*)(Wv2bf + n * 512 + koff);
#pragma unroll
            for (int mt = 0; mt < 4; ++mt)
                acc[mt][nt] = __builtin_amdgcn_mfma_f32_16x16x32_bf16(
                    afrag[mt], bfrag, acc[mt][nt], 0, 0, 0);
        }
    }

    float zp[16];
#pragma unroll
    for (int i = 0; i < 16; ++i) zp[i] = 0.f;
#pragma unroll
    for (int nt = 0; nt < 4; ++nt) {
        int n = (wave * 4 + nt) * 16 + l16;
        float bias = bv2[n];
        float wnc = w2[n];
#pragma unroll
        for (int mt = 0; mt < 4; ++mt)
#pragma unroll
            for (int r = 0; r < 4; ++r)
                zp[mt * 4 + r] += fmaxf(acc[mt][nt][r] + bias, 0.f) * wnc;
    }
#pragma unroll
    for (int i = 0; i < 16; ++i) {
        float v = zp[i];
        v += __shfl_xor(v, 1, 64);
        v += __shfl_xor(v, 2, 64);
        v += __shfl_xor(v, 4, 64);
        v += __shfl_xor(v, 8, 64);
        zp[i] = v;
    }
    if (l16 == 0) {
#pragma unroll
        for (int mt = 0; mt < 4; ++mt)
#pragma unroll
            for (int r = 0; r < 4; ++r)
                if (mt < 3 || (quad == 3 && r == 3)) {
                    int row = ((mt == 3) ? 33 : mt * 16) + quad * 4 + r;
                    zbuf[wave][row] = zp[mt * 4 + r];
                }
    }
    __syncthreads();

    if (wave == 0) {
        int hw = lane;
        float z = zbuf[0][hw] + zbuf[1][hw] + zbuf[2][hw] + zbuf[3][hw] + bsp[0];
        float t = tanhf(z);
        float v = (hw < 49) ? t : -1e30f;
#pragma unroll
        for (int off = 32; off; off >>= 1) v = fmaxf(v, __shfl_xor(v, off, 64));
        float e = (hw < 49) ? __expf(t - v) : 0.f;
        float se = e;
#pragma unroll
        for (int off = 32; off; off >>= 1) se += __shfl_xor(se, off, 64);
        smwl[hw] = e / se;
    }
    __syncthreads();

#pragma unroll
    for (int rep = 0; rep < 2; ++rep) {
        int cidx = tid + rep * 256;
        int chb = cidx >> 3, jj = cidx & 7;
        float s = 0.f;
        for (int hw = 0; hw < 49; ++hw) {
            int chs = chb ^ (hw & 7);
            s += smwl[hw] * bf2f(Ct[hw * 512 + chs * 8 + jj]);
        }
        out[bt * 512 + cidx] = s;
    }
}

extern "C" void kernel_launch(void* const* d_in, const int* in_sizes, int n_in,
                              void* d_out, int out_size, void* d_ws, size_t ws_size,
                              hipStream_t stream) {
    const float* video = (const float*)d_in[0];
    const float* audio = (const float*)d_in[1];
    const float* Wv1 = (const float*)d_in[2];
    const float* bv1 = (const float*)d_in[3];
    const float* Wa1 = (const float*)d_in[4];
    const float* ba1 = (const float*)d_in[5];
    const float* Wb  = (const float*)d_in[6];
    const float* bb  = (const float*)d_in[7];
    const float* Wc  = (const float*)d_in[8];
    const float* bc  = (const float*)d_in[9];
    const float* Wv2 = (const float*)d_in[10];
    const float* bv2 = (const float*)d_in[11];
    const float* Wa2 = (const float*)d_in[12];
    const float* ba2 = (const float*)d_in[13];
    const float* Wsp = (const float*)d_in[14];
    const float* bsp = (const float*)d_in[15];
    float* out = (float*)d_out;

    // main path: videobf 128,450,560 + Wv1bf 524,288 + Wv2bf 262,144
    //            + 4 f32 arrays 18,350,080 = 147,587,072 bytes
    const size_t NEED = 147587072u;
    if (ws_size >= NEED) {
        unsigned short* videobf = (unsigned short*)d_ws;        // 64,225,280 shorts
        unsigned short* Wv1bf = videobf + 64225280;             // 262,144
        unsigned short* Wv2bf = Wv1bf + 262144;                 // 131,072
        float* fbase = (float*)(Wv2bf + 131072);
        float* aq1  = fbase;                    // [2560,512]
        float* aq2  = aq1 + 1310720;            // [2560,256]
        float* avq  = aq2 + 655360;             // [2560,512]
        float* cmul = avq + 1310720;            // [2560,512]

        k_front<<<5120, 256, 0, stream>>>(video, videobf, Wv1, Wv2, Wv1bf, Wv2bf,
                                          audio, Wa1, ba1, Wa2, ba2, aq1, aq2);
        k_chanatt_g<<<2560, 512, 0, stream>>>(videobf, Wv1bf, bv1, aq1, avq);
        k_mlp<<<640, 256, 0, stream>>>(avq, Wb, bb, Wc, bc, cmul);
        k_sgemm<<<1280, 512, 0, stream>>>(videobf, cmul, aq2, Wv2bf, bv2, Wsp, bsp, out);
    } else {
        float* ws = (float*)d_ws;
        float* aq1  = ws;                       // [2560,512]
        float* aq2  = aq1 + 1310720;            // [2560,256]
        float* avq  = aq2 + 655360;             // [2560,512]
        float* cmul = avq + 1310720;            // [2560,512]
        unsigned short* Wv1bf = (unsigned short*)(cmul + 1310720);  // 512x512
        unsigned short* Wv2bf = Wv1bf + 262144;                     // 256x512

        k_prep<<<1536, 256, 0, stream>>>(Wv1, Wv2, Wv1bf, Wv2bf);
        k_audio<<<640, 256, 0, stream>>>(audio, Wa1, ba1, Wa2, ba2, aq1, aq2);
        k_chanatt_fb<<<2560, 256, 0, stream>>>(video, Wv1bf, bv1, aq1, avq);
        k_mlp<<<640, 256, 0, stream>>>(avq, Wb, bb, Wc, bc, cmul);
        k_spatial_fb<<<2560, 256, 0, stream>>>(video, cmul, aq2, Wv2bf, bv2, Wsp, bsp, out);
    }
}

// Round 5
// 712.244 us; speedup vs baseline: 1.2759x; 1.0383x over previous
//
#include <hip/hip_runtime.h>

typedef __bf16 bf16x8 __attribute__((ext_vector_type(8)));
typedef float f32x4 __attribute__((ext_vector_type(4)));

__device__ __forceinline__ unsigned short f2bf(float f) {
    union { float f; unsigned int u; } x; x.f = f;
    unsigned int r = x.u + 0x7FFFu + ((x.u >> 16) & 1u);
    return (unsigned short)(r >> 16);
}
__device__ __forceinline__ float bf2f(unsigned short v) {
    union { unsigned int u; float f; } x; x.u = ((unsigned int)v) << 16; return x.f;
}
__device__ __forceinline__ unsigned int cvt_pk_bf16(float lo, float hi) {
    unsigned int r;
    asm("v_cvt_pk_bf16_f32 %0, %1, %2" : "=v"(r) : "v"(lo), "v"(hi));
    return r;
}
// async global->LDS, 16B per lane. LDS dest must be lane-linear within a wave.
__device__ __forceinline__ void async16(const void* g, void* l) {
    __builtin_amdgcn_global_load_lds(
        (const __attribute__((address_space(1))) unsigned int*)g,
        (__attribute__((address_space(3))) unsigned int*)l, 16, 0, 0);
}

// ---------------- k_front: fused {Wv1/Wv2 fp32->bf16, audio MLP}.
// blocks [0,384): weight convert; [384,1024): audio.
__global__ __launch_bounds__(256) void k_front(
    const float* __restrict__ Wv1, const float* __restrict__ Wv2,
    unsigned short* __restrict__ Wv1bf, unsigned short* __restrict__ Wv2bf,
    const float* __restrict__ audio,
    const float* __restrict__ Wa1, const float* __restrict__ ba1,
    const float* __restrict__ Wa2, const float* __restrict__ ba2,
    float* __restrict__ aq1, float* __restrict__ aq2)
{
    const int b = blockIdx.x;
    const int tid = threadIdx.x;
    if (b < 384) {
        // weights: 393,216 elems, 1024 per block
        int base = b * 1024 + tid;
#pragma unroll
        for (int r = 0; r < 4; ++r) {
            int idx = base + r * 256;
            if (idx < 262144) Wv1bf[idx] = f2bf(Wv1[idx]);
            else              Wv2bf[idx - 262144] = f2bf(Wv2[idx - 262144]);
        }
        return;
    }
    // audio: aq1 = relu(af@Wa1^T+ba1), aq2 = relu(af@Wa2^T+ba2)
    __shared__ float afs[4][128];
    const int btBase = (b - 384) * 4;
    for (int i = tid; i < 512; i += 256) {
        int g = i >> 7, k = i & 127;
        int bt = btBase + g;
        int bb_ = bt / 10, t = bt - bb_ * 10;
        afs[g][k] = audio[(t * 256 + bb_) * 128 + k];
    }
    __syncthreads();
    const int c = tid;
    float a1a[4] = {0.f,0.f,0.f,0.f}, a1b[4] = {0.f,0.f,0.f,0.f}, a2[4] = {0.f,0.f,0.f,0.f};
    const float* w1a = Wa1 + c * 128;
    const float* w1b = Wa1 + (c + 256) * 128;
    const float* w2p = Wa2 + c * 128;
    for (int kk = 0; kk < 32; ++kk) {
        float4 va = *(const float4*)(w1a + kk * 4);
        float4 vb = *(const float4*)(w1b + kk * 4);
        float4 vc = *(const float4*)(w2p + kk * 4);
        float fa[4] = {va.x, va.y, va.z, va.w};
        float fb[4] = {vb.x, vb.y, vb.z, vb.w};
        float fc[4] = {vc.x, vc.y, vc.z, vc.w};
#pragma unroll
        for (int j = 0; j < 4; ++j) {
            int k = kk * 4 + j;
#pragma unroll
            for (int g = 0; g < 4; ++g) {
                float a = afs[g][k];
                a1a[g] += a * fa[j];
                a1b[g] += a * fb[j];
                a2[g]  += a * fc[j];
            }
        }
    }
    float b1a = ba1[c], b1b = ba1[c + 256], b2 = ba2[c];
#pragma unroll
    for (int g = 0; g < 4; ++g) {
        int bt = btBase + g;
        aq1[bt * 512 + c]       = fmaxf(a1a[g] + b1a, 0.f);
        aq1[bt * 512 + c + 256] = fmaxf(a1b[g] + b1b, 0.f);
        aq2[bt * 256 + c]       = fmaxf(a2[g] + b2, 0.f);
    }
}

// ---------------- Kernel 2: channel-attention GEMM.
// Grid: 1280 M-blocks (2 bt, rows padded to 64) x 2 N-halves. 512 threads, 8 waves (2M x 4N).
// A: fp32 video reg-staged -> bf16 LDS (T14 issue-early/write-late). B: async bf16 in LDS.
// Epilogue: per-bt mean over 49 real rows of relu(.+bias), * aq1 -> avq.
__global__ __launch_bounds__(512) void k_chanatt_g(
    const float* __restrict__ video,
    const unsigned short* __restrict__ Wv1bf, const float* __restrict__ bv1,
    const float* __restrict__ aq1, float* __restrict__ avq)
{
    // per buffer: A 128x32 (4096 shorts) | B 256x32 (8192 shorts) = 12288 shorts
    __shared__ unsigned short lds[2 * 12288];
    const int tid = threadIdx.x;
    const int wave = tid >> 6, lane = tid & 63, quad = lane >> 4, l16 = lane & 15;
    const int wm = wave >> 2, wn = wave & 3;
    const int mb = blockIdx.x >> 1, nb = blockIdx.x & 1;
    const int bt0 = mb * 2;

    // ---- A staging state (T14 split) ----
    const int arow = tid >> 2, ac = tid & 3;
    const int ahw = arow & 63, abtl = arow >> 6;
    const bool aok = (ahw < 49);
    const int aswz = (ac ^ (arow & 3)) << 3;
    const float* avsrc = video + (size_t)(bt0 + abtl) * 25088 + ahw * 512;
    float4 va, vb;

    auto aload = [&](int kt) {
        if (aok) {
            int k0 = kt * 32 + aswz;
            va = *(const float4*)(avsrc + k0);
            vb = *(const float4*)(avsrc + k0 + 4);
        }
    };
    auto awrite = [&](int buf) {
        if (aok) {
            uint4 o;
            o.x = cvt_pk_bf16(va.x, va.y); o.y = cvt_pk_bf16(va.z, va.w);
            o.z = cvt_pk_bf16(vb.x, vb.y); o.w = cvt_pk_bf16(vb.z, vb.w);
            *(uint4*)&lds[buf * 12288 + tid * 8] = o;
        }
    };
    auto stageB = [&](int buf, int kt) {
#pragma unroll
        for (int rep = 0; rep < 2; ++rep) {
            int q = tid + rep * 512;
            int row = q >> 2, c = q & 3;
            async16(Wv1bf + (size_t)((nb << 8) + row) * 512
                          + kt * 32 + ((c ^ (row & 3)) << 3),
                    &lds[buf * 12288 + 4096 + q * 8]);
        }
    };

    f32x4 acc[4][4];
#pragma unroll
    for (int mt = 0; mt < 4; ++mt)
#pragma unroll
        for (int nt = 0; nt < 4; ++nt)
            acc[mt][nt] = (f32x4){0.f, 0.f, 0.f, 0.f};

    aload(0);
    stageB(0, 0);
    awrite(0);
    __syncthreads();

    for (int kt = 0; kt < 16; ++kt) {
        int cur = kt & 1;
        if (kt < 15) { aload(kt + 1); stageB(cur ^ 1, kt + 1); }
        const int cb = cur * 12288;
        bf16x8 af[4];
#pragma unroll
        for (int mt = 0; mt < 4; ++mt) {
            int row = wm * 64 + mt * 16 + l16;
            af[mt] = *(const bf16x8*)&lds[cb + row * 32 + ((quad ^ (row & 3)) << 3)];
        }
#pragma unroll
        for (int nt = 0; nt < 4; ++nt) {
            int rowb = wn * 64 + nt * 16 + l16;
            bf16x8 bfr = *(const bf16x8*)&lds[cb + 4096 + rowb * 32 + ((quad ^ (rowb & 3)) << 3)];
#pragma unroll
            for (int mt = 0; mt < 4; ++mt)
                acc[mt][nt] = __builtin_amdgcn_mfma_f32_16x16x32_bf16(
                    af[mt], bfr, acc[mt][nt], 0, 0, 0);
        }
        if (kt < 15) awrite(cur ^ 1);
        __syncthreads();
    }

    const int bt = bt0 + wm;
#pragma unroll
    for (int nt = 0; nt < 4; ++nt) {
        int n = nb * 256 + wn * 64 + nt * 16 + l16;
        float bias = bv1[n];
        float s = 0.f;
#pragma unroll
        for (int mt = 0; mt < 4; ++mt)
#pragma unroll
            for (int r = 0; r < 4; ++r)
                if (mt < 3 || (quad == 0 && r == 0))   // rows 0..47 and row 48
                    s += fmaxf(acc[mt][nt][r] + bias, 0.f);
        s += __shfl_xor(s, 16, 64);
        s += __shfl_xor(s, 32, 64);
        if (quad == 0) {
            avq[bt * 512 + n] = aq1[bt * 512 + n] * (s * (1.f / 49.f));
        }
    }
}

// ---------------- Kernel 3: cmul = 1 + sigmoid( relu(avq@Wb^T+bb) @ Wc^T + bc )
__global__ __launch_bounds__(256) void k_mlp(
    const float* __restrict__ avq,
    const float* __restrict__ Wb, const float* __restrict__ bb,
    const float* __restrict__ Wc, const float* __restrict__ bc,
    float* __restrict__ cmul)
{
    __shared__ float av[4][512];
    __shared__ float hid[4][256];
    const int btBase = blockIdx.x * 4;
    const int tid = threadIdx.x;
    for (int i = tid; i < 2048; i += 256) {
        int g = i >> 9, c = i & 511;
        av[g][c] = avq[(btBase + g) * 512 + c];
    }
    __syncthreads();
    {
        float a[4] = {0.f,0.f,0.f,0.f};
        const float* wrow = Wb + tid * 512;
        for (int kk = 0; kk < 128; ++kk) {
            float4 v = *(const float4*)(wrow + kk * 4);
            float w[4] = {v.x, v.y, v.z, v.w};
#pragma unroll
            for (int j = 0; j < 4; ++j)
#pragma unroll
                for (int g = 0; g < 4; ++g)
                    a[g] += av[g][kk * 4 + j] * w[j];
        }
        float bias = bb[tid];
#pragma unroll
        for (int g = 0; g < 4; ++g) hid[g][tid] = fmaxf(a[g] + bias, 0.f);
    }
    __syncthreads();
#pragma unroll
    for (int rep = 0; rep < 2; ++rep) {
        int c = tid + rep * 256;
        float a[4] = {0.f,0.f,0.f,0.f};
        const float* wrow = Wc + c * 256;
        for (int kk = 0; kk < 64; ++kk) {
            float4 v = *(const float4*)(wrow + kk * 4);
            float w[4] = {v.x, v.y, v.z, v.w};
#pragma unroll
            for (int j = 0; j < 4; ++j)
#pragma unroll
                for (int g = 0; g < 4; ++g)
                    a[g] += hid[g][kk * 4 + j] * w[j];
        }
        float bias = bc[c];
#pragma unroll
        for (int g = 0; g < 4; ++g) {
            float s = 1.f / (1.f + __expf(-(a[g] + bias)));
            cmul[(btBase + g) * 512 + c] = 1.f + s;
        }
    }
}

// ---------------- Kernel 4: spatial GEMM + softmax + fused output contraction.
// Grid: 1280 blocks (2 bt, rows padded to 64). 512 threads, 8 waves (2M x 4N).
// A = fp32 video * cmul, reg-staged -> bf16 LDS (T14 split). B async in LDS.
// Tail: smw in LDS; out[bt,c] = cmul[bt,c]*sum_hw smw[hw]*video[bt,hw,c].
__global__ __launch_bounds__(512) void k_sgemm(
    const float* __restrict__ video,
    const float* __restrict__ cmul, const float* __restrict__ aq2,
    const unsigned short* __restrict__ Wv2bf, const float* __restrict__ bv2,
    const float* __restrict__ Wsp, const float* __restrict__ bsp,
    float* __restrict__ out)
{
    __shared__ unsigned short lds[2 * 12288];   // A 4096 | B 8192 per buffer
    __shared__ float zsh[8][64];
    __shared__ float smloc[2][64];
    const int tid = threadIdx.x;
    const int wave = tid >> 6, lane = tid & 63, quad = lane >> 4, l16 = lane & 15;
    const int wm = wave >> 2, wn = wave & 3;
    const int bt0 = blockIdx.x * 2;

    // ---- A staging state (T14 split) ----
    const int arow = tid >> 2, ac = tid & 3;
    const int ahw = arow & 63, abtl = arow >> 6;
    const bool aok = (ahw < 49);
    const int aswz = (ac ^ (arow & 3)) << 3;
    const float* avsrc = video + (size_t)(bt0 + abtl) * 25088 + ahw * 512;
    const float* acm = cmul + (bt0 + abtl) * 512;
    float4 va, vb;
    float4 c0reg, c1reg;

    auto aload = [&](int kt) {
        if (aok) {
            int k0 = kt * 32 + aswz;
            va = *(const float4*)(avsrc + k0);
            vb = *(const float4*)(avsrc + k0 + 4);
            c0reg = *(const float4*)(acm + k0);
            c1reg = *(const float4*)(acm + k0 + 4);
        }
    };
    auto awrite = [&](int buf) {
        if (aok) {
            uint4 o;
            o.x = cvt_pk_bf16(va.x * c0reg.x, va.y * c0reg.y);
            o.y = cvt_pk_bf16(va.z * c0reg.z, va.w * c0reg.w);
            o.z = cvt_pk_bf16(vb.x * c1reg.x, vb.y * c1reg.y);
            o.w = cvt_pk_bf16(vb.z * c1reg.z, vb.w * c1reg.w);
            *(uint4*)&lds[buf * 12288 + tid * 8] = o;
        }
    };
    auto stageB = [&](int buf, int kt) {
#pragma unroll
        for (int rep = 0; rep < 2; ++rep) {
            int q = tid + rep * 512;
            int row = q >> 2, c = q & 3;
            async16(Wv2bf + (size_t)row * 512 + kt * 32 + ((c ^ (row & 3)) << 3),
                    &lds[buf * 12288 + 4096 + q * 8]);
        }
    };

    f32x4 acc[4][4];
#pragma unroll
    for (int mt = 0; mt < 4; ++mt)
#pragma unroll
        for (int nt = 0; nt < 4; ++nt)
            acc[mt][nt] = (f32x4){0.f, 0.f, 0.f, 0.f};

    aload(0);
    stageB(0, 0);
    awrite(0);
    __syncthreads();

    for (int kt = 0; kt < 16; ++kt) {
        int cur = kt & 1;
        if (kt < 15) { aload(kt + 1); stageB(cur ^ 1, kt + 1); }
        const int cb = cur * 12288;
        bf16x8 af[4];
#pragma unroll
        for (int mt = 0; mt < 4; ++mt) {
            int row = wm * 64 + mt * 16 + l16;
            af[mt] = *(const bf16x8*)&lds[cb + row * 32 + ((quad ^ (row & 3)) << 3)];
        }
#pragma unroll
        for (int nt = 0; nt < 4; ++nt) {
            int rowb = wn * 64 + nt * 16 + l16;
            bf16x8 bfr = *(const bf16x8*)&lds[cb + 4096 + rowb * 32 + ((quad ^ (rowb & 3)) << 3)];
#pragma unroll
            for (int mt = 0; mt < 4; ++mt)
                acc[mt][nt] = __builtin_amdgcn_mfma_f32_16x16x32_bf16(
                    af[mt], bfr, acc[mt][nt], 0, 0, 0);
        }
        if (kt < 15) awrite(cur ^ 1);
        __syncthreads();
    }

    // z-partials
    const int bt = bt0 + wm;
    float zp[16];
#pragma unroll
    for (int i = 0; i < 16; ++i) zp[i] = 0.f;
#pragma unroll
    for (int nt = 0; nt < 4; ++nt) {
        int n = wn * 64 + nt * 16 + l16;
        float bias = bv2[n];
        float co = aq2[bt * 256 + n] * Wsp[n];
#pragma unroll
        for (int mt = 0; mt < 4; ++mt)
#pragma unroll
            for (int r = 0; r < 4; ++r)
                zp[mt * 4 + r] += fmaxf(acc[mt][nt][r] + bias, 0.f) * co;
    }
#pragma unroll
    for (int i = 0; i < 16; ++i) {
        float v = zp[i];
        v += __shfl_xor(v, 1, 64);
        v += __shfl_xor(v, 2, 64);
        v += __shfl_xor(v, 4, 64);
        v += __shfl_xor(v, 8, 64);
        zp[i] = v;
    }
    if (l16 == 0) {
#pragma unroll
        for (int mt = 0; mt < 4; ++mt)
#pragma unroll
            for (int r = 0; r < 4; ++r)
                zsh[wave][mt * 16 + quad * 4 + r] = zp[mt * 4 + r];
    }
    __syncthreads();

    if (wn == 0) {    // waves 0 (bt0) and 4 (bt0+1)
        int hw = lane;
        float z = zsh[wm * 4 + 0][hw] + zsh[wm * 4 + 1][hw]
                + zsh[wm * 4 + 2][hw] + zsh[wm * 4 + 3][hw] + bsp[0];
        float t = tanhf(z);
        float v = (hw < 49) ? t : -1e30f;
#pragma unroll
        for (int off = 32; off; off >>= 1) v = fmaxf(v, __shfl_xor(v, off, 64));
        float e = (hw < 49) ? __expf(t - v) : 0.f;
        float se = e;
#pragma unroll
        for (int off = 32; off; off >>= 1) se += __shfl_xor(se, off, 64);
        smloc[wm][hw] = (hw < 49) ? (e / se) : 0.f;
    }
    __syncthreads();

    // fused output: group g (btl, 8-channel chunk), 4 threads split hw
    {
        int g = tid >> 2, part = tid & 3;
        int btl = g >> 6, cg = g & 63;
        const float* vs = video + (size_t)(bt0 + btl) * 25088 + cg * 8;
        float s[8];
#pragma unroll
        for (int j = 0; j < 8; ++j) s[j] = 0.f;
        for (int hw = part; hw < 49; hw += 4) {
            float w = smloc[btl][hw];
            float4 v0 = *(const float4*)(vs + hw * 512);
            float4 v1 = *(const float4*)(vs + hw * 512 + 4);
            s[0] += w * v0.x; s[1] += w * v0.y;
            s[2] += w * v0.z; s[3] += w * v0.w;
            s[4] += w * v1.x; s[5] += w * v1.y;
            s[6] += w * v1.z; s[7] += w * v1.w;
        }
#pragma unroll
        for (int j = 0; j < 8; ++j) {
            s[j] += __shfl_xor(s[j], 1, 64);
            s[j] += __shfl_xor(s[j], 2, 64);
        }
        if (part == 0) {
            const float* cm = cmul + (bt0 + btl) * 512 + cg * 8;
            float4 m0 = *(const float4*)cm;
            float4 m1 = *(const float4*)(cm + 4);
            float mm[8] = {m0.x, m0.y, m0.z, m0.w, m1.x, m1.y, m1.z, m1.w};
            float* op = out + (bt0 + btl) * 512 + cg * 8;
#pragma unroll
            for (int j = 0; j < 8; ++j) op[j] = s[j] * mm[j];
        }
    }
}

// ================= Fallback path (fp32 video, known-good) =================
__global__ __launch_bounds__(256) void k_prep(
    const float* __restrict__ Wv1, const float* __restrict__ Wv2,
    unsigned short* __restrict__ Wv1bf, unsigned short* __restrict__ Wv2bf)
{
    int idx = blockIdx.x * 256 + threadIdx.x;
    if (idx < 262144) {
        Wv1bf[idx] = f2bf(Wv1[idx]);
    } else {
        int j = idx - 262144;
        Wv2bf[j] = f2bf(Wv2[j]);
    }
}

__global__ __launch_bounds__(256) void k_audio(
    const float* __restrict__ audio,
    const float* __restrict__ Wa1, const float* __restrict__ ba1,
    const float* __restrict__ Wa2, const float* __restrict__ ba2,
    float* __restrict__ aq1, float* __restrict__ aq2)
{
    __shared__ float afs[4][128];
    const int btBase = blockIdx.x * 4;
    const int tid = threadIdx.x;
    for (int i = tid; i < 512; i += 256) {
        int g = i >> 7, k = i & 127;
        int bt = btBase + g;
        int b = bt / 10, t = bt - b * 10;
        afs[g][k] = audio[(t * 256 + b) * 128 + k];
    }
    __syncthreads();
    const int c = tid;
    float a1a[4] = {0.f,0.f,0.f,0.f}, a1b[4] = {0.f,0.f,0.f,0.f}, a2[4] = {0.f,0.f,0.f,0.f};
    const float* w1a = Wa1 + c * 128;
    const float* w1b = Wa1 + (c + 256) * 128;
    const float* w2p = Wa2 + c * 128;
    for (int kk = 0; kk < 32; ++kk) {
        float4 va = *(const float4*)(w1a + kk * 4);
        float4 vb = *(const float4*)(w1b + kk * 4);
        float4 vc = *(const float4*)(w2p + kk * 4);
        float fa[4] = {va.x, va.y, va.z, va.w};
        float fb[4] = {vb.x, vb.y, vb.z, vb.w};
        float fc[4] = {vc.x, vc.y, vc.z, vc.w};
#pragma unroll
        for (int j = 0; j < 4; ++j) {
            int k = kk * 4 + j;
#pragma unroll
            for (int g = 0; g < 4; ++g) {
                float a = afs[g][k];
                a1a[g] += a * fa[j];
                a1b[g] += a * fb[j];
                a2[g]  += a * fc[j];
            }
        }
    }
    float b1a = ba1[c], b1b = ba1[c + 256], b2 = ba2[c];
#pragma unroll
    for (int g = 0; g < 4; ++g) {
        int bt = btBase + g;
        aq1[bt * 512 + c]       = fmaxf(a1a[g] + b1a, 0.f);
        aq1[bt * 512 + c + 256] = fmaxf(a1b[g] + b1b, 0.f);
        aq2[bt * 256 + c]       = fmaxf(a2[g] + b2, 0.f);
    }
}

__global__ __launch_bounds__(256) void k_chanatt_fb(
    const float* __restrict__ video,
    const unsigned short* __restrict__ Wv1bf, const float* __restrict__ bv1,
    const float* __restrict__ aq1, float* __restrict__ avq)
{
    __shared__ unsigned short At[49 * 512];
    const int bt = blockIdx.x;
    const int tid = threadIdx.x;
    const int wave = tid >> 6, lane = tid & 63, quad = lane >> 4, l16 = lane & 15;
    const float* vsrc = video + (size_t)bt * 25088;

    for (int c = tid; c < 3136; c += 256) {
        int row = c >> 6, ch = c & 63;
        float4 a = *(const float4*)(vsrc + row * 512 + ch * 8);
        float4 b = *(const float4*)(vsrc + row * 512 + ch * 8 + 4);
        float f[8] = {a.x, a.y, a.z, a.w, b.x, b.y, b.z, b.w};
        unsigned int o[8];
#pragma unroll
        for (int j = 0; j < 8; ++j) o[j] = f2bf(f[j]);
        uint4 pack;
        pack.x = o[0] | (o[1] << 16); pack.y = o[2] | (o[3] << 16);
        pack.z = o[4] | (o[5] << 16); pack.w = o[6] | (o[7] << 16);
        int chs = ch ^ (row & 7);
        *(uint4*)(&At[row * 512 + chs * 8]) = pack;
    }
    __syncthreads();

    f32x4 acc[4][8];
#pragma unroll
    for (int mt = 0; mt < 4; ++mt)
#pragma unroll
        for (int nt = 0; nt < 8; ++nt)
            acc[mt][nt] = (f32x4){0.f, 0.f, 0.f, 0.f};

    for (int kk = 0; kk < 16; ++kk) {
        int chunk = kk * 4 + quad;
        bf16x8 afrag[4];
#pragma unroll
        for (int mt = 0; mt < 4; ++mt) {
            int m = ((mt == 3) ? 33 : mt * 16) + l16;
            int chs = chunk ^ (m & 7);
            afrag[mt] = *(const bf16x8*)(&At[m * 512 + chs * 8]);
        }
        int koff = chunk * 8;
#pragma unroll
        for (int nt = 0; nt < 8; ++nt) {
            int n = (wave * 8 + nt) * 16 + l16;
            bf16x8 bfrag = *(const bf16x8*)(Wv1bf + n * 512 + koff);
#pragma unroll
            for (int mt = 0; mt < 4; ++mt)
                acc[mt][nt] = __builtin_amdgcn_mfma_f32_16x16x32_bf16(
                    afrag[mt], bfrag, acc[mt][nt], 0, 0, 0);
        }
    }

#pragma unroll
    for (int nt = 0; nt < 8; ++nt) {
        int n = (wave * 8 + nt) * 16 + l16;
        float bias = bv1[n];
        float s = 0.f;
#pragma unroll
        for (int mt = 0; mt < 4; ++mt)
#pragma unroll
            for (int r = 0; r < 4; ++r)
                if (mt < 3 || (quad == 3 && r == 3))
                    s += fmaxf(acc[mt][nt][r] + bias, 0.f);
        s += __shfl_xor(s, 16, 64);
        s += __shfl_xor(s, 32, 64);
        if (quad == 0) {
            float vm = s * (1.f / 49.f);
            avq[bt * 512 + n] = aq1[bt * 512 + n] * vm;
        }
    }
}

__global__ __launch_bounds__(256) void k_spatial_fb(
    const float* __restrict__ video,
    const float* __restrict__ cmul, const float* __restrict__ aq2,
    const unsigned short* __restrict__ Wv2bf, const float* __restrict__ bv2,
    const float* __restrict__ Wsp, const float* __restrict__ bsp,
    float* __restrict__ out)
{
    __shared__ unsigned short Ct[49 * 512];
    __shared__ float w2[256];
    __shared__ float zbuf[4][64];
    __shared__ float smwl[64];
    const int bt = blockIdx.x;
    const int tid = threadIdx.x;
    const int wave = tid >> 6, lane = tid & 63, quad = lane >> 4, l16 = lane & 15;
    const float* vsrc = video + (size_t)bt * 25088;
    const float* cm = cmul + bt * 512;

    for (int c = tid; c < 3136; c += 256) {
        int row = c >> 6, ch = c & 63;
        float4 a = *(const float4*)(vsrc + row * 512 + ch * 8);
        float4 b = *(const float4*)(vsrc + row * 512 + ch * 8 + 4);
        float f[8] = {a.x, a.y, a.z, a.w, b.x, b.y, b.z, b.w};
        float4 m0 = *(const float4*)(cm + ch * 8);
        float4 m1 = *(const float4*)(cm + ch * 8 + 4);
        float mm[8] = {m0.x, m0.y, m0.z, m0.w, m1.x, m1.y, m1.z, m1.w};
        unsigned int o[8];
#pragma unroll
        for (int j = 0; j < 8; ++j) o[j] = f2bf(f[j] * mm[j]);
        uint4 pack;
        pack.x = o[0] | (o[1] << 16); pack.y = o[2] | (o[3] << 16);
        pack.z = o[4] | (o[5] << 16); pack.w = o[6] | (o[7] << 16);
        int chs = ch ^ (row & 7);
        *(uint4*)(&Ct[row * 512 + chs * 8]) = pack;
    }
    w2[tid] = aq2[bt * 256 + tid] * Wsp[tid];
    if (lane >= 49) zbuf[wave][lane] = 0.f;
    __syncthreads();

    f32x4 acc[4][4];
#pragma unroll
    for (int mt = 0; mt < 4; ++mt)
#pragma unroll
        for (int nt = 0; nt < 4; ++nt)
            acc[mt][nt] = (f32x4){0.f, 0.f, 0.f, 0.f};

    for (int kk = 0; kk < 16; ++kk) {
        int chunk = kk * 4 + quad;
        bf16x8 afrag[4];
#pragma unroll
        for (int mt = 0; mt < 4; ++mt) {
            int m = ((mt == 3) ? 33 : mt * 16) + l16;
            int chs = chunk ^ (m & 7);
            afrag[mt] = *(const bf16x8*)(&Ct[m * 512 + chs * 8]);
        }
        int koff = chunk * 8;
#pragma unroll
        for (int nt = 0; nt < 4; ++nt) {
            int n = (wave * 4 + nt) * 16 + l16;
            bf16x8 bfrag = *(const bf16x8*)(Wv2bf + n * 512 + koff);
#pragma unroll
            for (int mt = 0; mt < 4; ++mt)
                acc[mt][nt] = __builtin_amdgcn_mfma_f32_16x16x32_bf16(
                    afrag[mt], bfrag, acc[mt][nt], 0, 0, 0);
        }
    }

    float zp[16];
#pragma unroll
    for (int i = 0; i < 16; ++i) zp[i] = 0.f;
#pragma unroll
    for (int nt = 0; nt < 4; ++nt) {
        int n = (wave * 4 + nt) * 16 + l16;
        float bias = bv2[n];
        float wnc = w2[n];
#pragma unroll
        for (int mt = 0; mt < 4; ++mt)
#pragma unroll
            for (int r = 0; r < 4; ++r)
                zp[mt * 4 + r] += fmaxf(acc[mt][nt][r] + bias, 0.f) * wnc;
    }
#pragma unroll
    for (int i = 0; i < 16; ++i) {
        float v = zp[i];
        v += __shfl_xor(v, 1, 64);
        v += __shfl_xor(v, 2, 64);
        v += __shfl_xor(v, 4, 64);
        v += __shfl_xor(v, 8, 64);
        zp[i] = v;
    }
    if (l16 == 0) {
#pragma unroll
        for (int mt = 0; mt < 4; ++mt)
#pragma unroll
            for (int r = 0; r < 4; ++r)
                if (mt < 3 || (quad == 3 && r == 3)) {
                    int row = ((mt == 3) ? 33 : mt * 16) + quad * 4 + r;
                    zbuf[wave][row] = zp[mt * 4 + r];
                }
    }
    __syncthreads();

    if (wave == 0) {
        int hw = lane;
        float z = zbuf[0][hw] + zbuf[1][hw] + zbuf[2][hw] + zbuf[3][hw] + bsp[0];
        float t = tanhf(z);
        float v = (hw < 49) ? t : -1e30f;
#pragma unroll
        for (int off = 32; off; off >>= 1) v = fmaxf(v, __shfl_xor(v, off, 64));
        float e = (hw < 49) ? __expf(t - v) : 0.f;
        float se = e;
#pragma unroll
        for (int off = 32; off; off >>= 1) se += __shfl_xor(se, off, 64);
        smwl[hw] = e / se;
    }
    __syncthreads();

#pragma unroll
    for (int rep = 0; rep < 2; ++rep) {
        int cidx = tid + rep * 256;
        int chb = cidx >> 3, jj = cidx & 7;
        float s = 0.f;
        for (int hw = 0; hw < 49; ++hw) {
            int chs = chb ^ (hw & 7);
            s += smwl[hw] * bf2f(Ct[hw * 512 + chs * 8 + jj]);
        }
        out[bt * 512 + cidx] = s;
    }
}

extern "C" void kernel_launch(void* const* d_in, const int* in_sizes, int n_in,
                              void* d_out, int out_size, void* d_ws, size_t ws_size,
                              hipStream_t stream) {
    const float* video = (const float*)d_in[0];
    const float* audio = (const float*)d_in[1];
    const float* Wv1 = (const float*)d_in[2];
    const float* bv1 = (const float*)d_in[3];
    const float* Wa1 = (const float*)d_in[4];
    const float* ba1 = (const float*)d_in[5];
    const float* Wb  = (const float*)d_in[6];
    const float* bb  = (const float*)d_in[7];
    const float* Wc  = (const float*)d_in[8];
    const float* bc  = (const float*)d_in[9];
    const float* Wv2 = (const float*)d_in[10];
    const float* bv2 = (const float*)d_in[11];
    const float* Wa2 = (const float*)d_in[12];
    const float* ba2 = (const float*)d_in[13];
    const float* Wsp = (const float*)d_in[14];
    const float* bsp = (const float*)d_in[15];
    float* out = (float*)d_out;

    // main path: Wv1bf 524,288 + Wv2bf 262,144 + 4 f32 arrays 18,350,080 = 19,136,512 bytes
    const size_t NEED = 19136512u;
    if (ws_size >= NEED) {
        unsigned short* Wv1bf = (unsigned short*)d_ws;          // 262,144 shorts
        unsigned short* Wv2bf = Wv1bf + 262144;                 // 131,072
        float* fbase = (float*)(Wv2bf + 131072);
        float* aq1  = fbase;                    // [2560,512]
        float* aq2  = aq1 + 1310720;            // [2560,256]
        float* avq  = aq2 + 655360;             // [2560,512]
        float* cmul = avq + 1310720;            // [2560,512]

        k_front<<<1024, 256, 0, stream>>>(Wv1, Wv2, Wv1bf, Wv2bf,
                                          audio, Wa1, ba1, Wa2, ba2, aq1, aq2);
        k_chanatt_g<<<2560, 512, 0, stream>>>(video, Wv1bf, bv1, aq1, avq);
        k_mlp<<<640, 256, 0, stream>>>(avq, Wb, bb, Wc, bc, cmul);
        k_sgemm<<<1280, 512, 0, stream>>>(video, cmul, aq2, Wv2bf, bv2, Wsp, bsp, out);
    } else {
        float* ws = (float*)d_ws;
        float* aq1  = ws;                       // [2560,512]
        float* aq2  = aq1 + 1310720;            // [2560,256]
        float* avq  = aq2 + 655360;             // [2560,512]
        float* cmul = avq + 1310720;            // [2560,512]
        unsigned short* Wv1bf = (unsigned short*)(cmul + 1310720);  // 512x512
        unsigned short* Wv2bf = Wv1bf + 262144;                     // 256x512

        k_prep<<<1536, 256, 0, stream>>>(Wv1, Wv2, Wv1bf, Wv2bf);
        k_audio<<<640, 256, 0, stream>>>(audio, Wa1, ba1, Wa2, ba2, aq1, aq2);
        k_chanatt_fb<<<2560, 256, 0, stream>>>(video, Wv1bf, bv1, aq1, avq);
        k_mlp<<<640, 256, 0, stream>>>(avq, Wb, bb, Wc, bc, cmul);
        k_spatial_fb<<<2560, 256, 0, stream>>>(video, cmul, aq2, Wv2bf, bv2, Wsp, bsp, out);
    }
}